// Round 3
// baseline (11382.140 us; speedup 1.0000x reference)
//
#include <hip/hip_runtime.h>

#define NCONV_DEF 4
#define SCH 1024

typedef unsigned short u16;

__device__ __forceinline__ float sigm_f(float x){ return 1.f/(1.f+__expf(-x)); }
__device__ __forceinline__ float silu_f(float x){ return x/(1.f+__expf(-x)); }
__device__ __forceinline__ float b2f(u16 h){ union{unsigned u; float f;} v; v.u=(unsigned)h<<16; return v.f; }
__device__ __forceinline__ u16 f2b(float f){ union{float f; unsigned u;} v; v.f=f; unsigned r=v.u+0x7fffu+((v.u>>16)&1u); return (u16)(r>>16); }
__device__ __forceinline__ float ldA(const float* p, size_t i){ return p[i]; }
__device__ __forceinline__ float ldA(const u16* p, size_t i){ return b2f(p[i]); }

__global__ __launch_bounds__(256) void zero_f_k(float* p, long n){
    long i=(long)blockIdx.x*256+threadIdx.x, st=(long)gridDim.x*256;
    for(;i<n;i+=st) p[i]=0.f;
}
__global__ __launch_bounds__(256) void zero_i_k(int* p, long n){
    long i=(long)blockIdx.x*256+threadIdx.x, st=(long)gridDim.x*256;
    for(;i<n;i+=st) p[i]=0;
}
__global__ void diag_k(float* out, int n, float v){
    int i=blockIdx.x*256+threadIdx.x; if(i<n) out[i]=v;
}
__global__ void probe_k(const int* ei, const int* eil, const int* batch, int nb, int* flag){
    if(threadIdx.x||blockIdx.x) return;
    int a=2,b=2,c=2;
    for(int k=0;k<64;k++){ if(ei[2*k+1]!=0) a=1; if(eil[2*k+1]!=0) b=1; }
    int base=nb-128;
    for(int k=0;k<64;k++){ if(batch[base+2*k+1]!=0) c=1; }
    flag[0]=a; flag[1]=b; flag[2]=c;
}

__global__ __launch_bounds__(256)
void hist_k(const int* __restrict__ idx, const int* __restrict__ iflag, int fi,
            int* __restrict__ cnt, int Ne, int Nn){
    int e=blockIdx.x*256+threadIdx.x; if(e>=Ne) return;
    int st=iflag[fi];
    int i=idx[(size_t)e*st]; i=i<0?0:(i>=Nn?Nn-1:i);
    atomicAdd(&cnt[i],1);
}
__global__ __launch_bounds__(256)
void scan1_k(const int* cnt, int* tot, int n){
    __shared__ int sh[256];
    int base=blockIdx.x*SCH, s=0;
    for(int t=threadIdx.x;t<SCH;t+=256){ int i=base+t; s+=(i<n)?cnt[i]:0; }
    sh[threadIdx.x]=s; __syncthreads();
    for(int o=128;o;o>>=1){ if(threadIdx.x<o) sh[threadIdx.x]+=sh[threadIdx.x+o]; __syncthreads(); }
    if(threadIdx.x==0) tot[blockIdx.x]=sh[0];
}
__global__ void scan2_k(int* tot, int nb){
    if(threadIdx.x==0&&blockIdx.x==0){ int acc=0; for(int i=0;i<nb;i++){int v=tot[i]; tot[i]=acc; acc+=v;} }
}
__global__ __launch_bounds__(256)
void scan3_k(const int* cnt, const int* tot, int* off, int n, int total){
    __shared__ int sh[256];
    int b=blockIdx.x, t4=b*SCH+threadIdx.x*4;
    int v0=(t4+0<n)?cnt[t4+0]:0, v1=(t4+1<n)?cnt[t4+1]:0;
    int v2=(t4+2<n)?cnt[t4+2]:0, v3=(t4+3<n)?cnt[t4+3]:0;
    int ls=v0+v1+v2+v3;
    sh[threadIdx.x]=ls; __syncthreads();
    for(int o=1;o<256;o<<=1){
        int val=(threadIdx.x>=o)?sh[threadIdx.x-o]:0; __syncthreads();
        sh[threadIdx.x]+=val; __syncthreads();
    }
    int excl=sh[threadIdx.x]-ls+tot[b];
    if(t4+0<n) off[t4+0]=excl;
    if(t4+1<n) off[t4+1]=excl+v0;
    if(t4+2<n) off[t4+2]=excl+v0+v1;
    if(t4+3<n) off[t4+3]=excl+v0+v1+v2;
    if(b==(int)gridDim.x-1&&threadIdx.x==255) off[n]=total;
}
__global__ __launch_bounds__(256)
void fill_k(const int* __restrict__ idx, const int* __restrict__ iflag, int fi,
            const int* __restrict__ off, int* __restrict__ cur, int* __restrict__ list,
            int Ne, int Nn){
    int e=blockIdx.x*256+threadIdx.x; if(e>=Ne) return;
    int st=iflag[fi];
    int i=idx[(size_t)e*st]; i=i<0?0:(i>=Nn?Nn-1:i);
    int pos=off[i]+atomicAdd(&cur[i],1);
    list[pos]=e;
}

template<typename TA, int ACT>
__global__ __launch_bounds__(256)
void gemm_k(const TA* __restrict__ A, int lda, int M, int K,
            const float* __restrict__ W, const float* __restrict__ bias,
            u16* __restrict__ C)
{
    __shared__ __align__(16) float As[64*68];
    __shared__ __align__(16) float Ws[64*132];
    const int tid=threadIdx.x, row0=blockIdx.x*64;
    const int ty=tid>>4, tx=tid&15;
    float acc[4][8];
#pragma unroll
    for(int r=0;r<4;++r)
#pragma unroll
        for(int c=0;c<8;++c) acc[r][c]=0.f;

    for(int kt=0;kt<K;kt+=64){
        const int kc=K-kt;
        for(int idx=tid;idx<64*64;idx+=256){
            int r=idx>>6,k=idx&63,gr=row0+r;
            float v=0.f;
            if(gr<M&&k<kc) v=ldA(A,(size_t)gr*lda+kt+k);
            As[r*68+k]=v;
        }
        for(int idx=tid;idx<64*128;idx+=256){
            int k=idx>>7,c=idx&127;
            float v=0.f;
            if(k<kc) v=W[(size_t)(kt+k)*128+c];
            Ws[k*132+c]=v;
        }
        __syncthreads();
#pragma unroll 4
        for(int k0=0;k0<64;k0+=4){
            float4 a[4],bl[4],bh[4];
#pragma unroll
            for(int r=0;r<4;++r) a[r]=*(const float4*)&As[(ty*4+r)*68+k0];
#pragma unroll
            for(int kk=0;kk<4;++kk){
                bl[kk]=*(const float4*)&Ws[(k0+kk)*132+tx*4];
                bh[kk]=*(const float4*)&Ws[(k0+kk)*132+64+tx*4];
            }
#pragma unroll
            for(int r=0;r<4;++r){
                float4 av=a[r];
                acc[r][0]+=av.x*bl[0].x+av.y*bl[1].x+av.z*bl[2].x+av.w*bl[3].x;
                acc[r][1]+=av.x*bl[0].y+av.y*bl[1].y+av.z*bl[2].y+av.w*bl[3].y;
                acc[r][2]+=av.x*bl[0].z+av.y*bl[1].z+av.z*bl[2].z+av.w*bl[3].z;
                acc[r][3]+=av.x*bl[0].w+av.y*bl[1].w+av.z*bl[2].w+av.w*bl[3].w;
                acc[r][4]+=av.x*bh[0].x+av.y*bh[1].x+av.z*bh[2].x+av.w*bh[3].x;
                acc[r][5]+=av.x*bh[0].y+av.y*bh[1].y+av.z*bh[2].y+av.w*bh[3].y;
                acc[r][6]+=av.x*bh[0].z+av.y*bh[1].z+av.z*bh[2].z+av.w*bh[3].z;
                acc[r][7]+=av.x*bh[0].w+av.y*bh[1].w+av.z*bh[2].w+av.w*bh[3].w;
            }
        }
        __syncthreads();
    }
#pragma unroll
    for(int r=0;r<4;++r){
        int gr=row0+ty*4+r;
        if(gr>=M) continue;
        u16* crow=C+(size_t)gr*128;
#pragma unroll
        for(int cc=0;cc<4;++cc){
            float lo=acc[r][cc], hi=acc[r][4+cc];
            if(bias){ lo+=bias[tx*4+cc]; hi+=bias[64+tx*4+cc]; }
            if(ACT){ lo=silu_f(lo); hi=silu_f(hi); }
            crow[tx*4+cc]=f2b(lo);
            crow[64+tx*4+cc]=f2b(hi);
        }
    }
}

template<int FINAL>
__global__ __launch_bounds__(256)
void gather_k(const u16* __restrict__ x, u16* __restrict__ xnew,
              const u16* __restrict__ e, const u16* __restrict__ P1,
              const int* __restrict__ off, const int* __restrict__ list,
              const int* __restrict__ idx, long joff,
              const int* __restrict__ iflag, int fi,
              const float* __restrict__ g, const float* __restrict__ b,
              int Nn, int c0, int c1)
{
    int st=iflag[fi];
    int wid=threadIdx.x>>6, lane=threadIdx.x&63;
    int n=blockIdx.x*4+wid; if(n>=Nn) return;
    int beg=off[n], end=off[n+1];
    float es0=0.f, es1=0.f;
    for(int k=beg;k<end;++k){
        int eid=list[k];
        const u16* er=e+(size_t)eid*128;
        es0+=sigm_f(b2f(er[lane]));
        es1+=sigm_f(b2f(er[64+lane]));
    }
    float r0=1.f/(es0+1e-5f), r1=1.f/(es1+1e-5f);
    float a0=0.f, a1=0.f;
    for(int k=beg;k<end;++k){
        int eid=list[k];
        int j=idx[((size_t)joff+eid)*st]; j=j<0?0:(j>=Nn?Nn-1:j);
        if(j<c0||j>=c1) continue;
        const u16* er=e+(size_t)eid*128;
        const u16* pr=P1+(size_t)(j-c0)*128;
        a0+=sigm_f(b2f(er[lane]))*r0*b2f(pr[lane]);
        a1+=sigm_f(b2f(er[64+lane]))*r1*b2f(pr[64+lane]);
    }
    size_t ro=(size_t)n*128;
    float z0=b2f(xnew[ro+lane])+a0;
    float z1=b2f(xnew[ro+64+lane])+a1;
    if(!FINAL){
        xnew[ro+lane]=f2b(z0); xnew[ro+64+lane]=f2b(z1);
    } else {
        float s=z0+z1, q=z0*z0+z1*z1;
        for(int m=32;m;m>>=1){ s+=__shfl_xor(s,m,64); q+=__shfl_xor(q,m,64); }
        float mean=s*(1.f/128.f), var=q*(1.f/128.f)-mean*mean;
        float rstd=rsqrtf(var+1e-5f);
        float h0=g[lane]*(z0-mean)*rstd+b[lane];
        float h1=g[64+lane]*(z1-mean)*rstd+b[64+lane];
        xnew[ro+lane]   =f2b(b2f(x[ro+lane])   +silu_f(h0));
        xnew[ro+64+lane]=f2b(b2f(x[ro+64+lane])+silu_f(h1));
    }
}

__global__ __launch_bounds__(256)
void edgez_k(u16* __restrict__ e, const u16* __restrict__ x,
             const int* __restrict__ idx, long joff,
             const int* __restrict__ iflag, int fi,
             const float* __restrict__ We, const float* __restrict__ be,
             const float* __restrict__ g, const float* __restrict__ b,
             int Ne, int Nn)
{
    __shared__ __align__(16) float As[64*68];
    __shared__ __align__(16) float Ws[64*132];
    __shared__ int rid[128];
    const int tid=threadIdx.x, row0=blockIdx.x*64;
    int st=iflag[fi];
    if(tid<128){
        int r=tid&63, eid=row0+r; if(eid>=Ne) eid=Ne-1;
        long elem=(tid<64)?(long)eid:(joff+eid);
        int v=idx[(size_t)elem*st]; v=v<0?0:(v>=Nn?Nn-1:v);
        rid[tid]=v;
    }
    const int ty=tid>>4, tx=tid&15;
    float acc[4][8];
#pragma unroll
    for(int r=0;r<4;++r)
#pragma unroll
        for(int c=0;c<8;++c) acc[r][c]=0.f;

    for(int kt=0;kt<6;++kt){
        int sec=kt>>1, half=kt&1;
        __syncthreads();
#pragma unroll
        for(int u=0;u<2;++u){
            int unit=tid*2+u;
            int r=unit>>3, cg=unit&7;
            const u16* src;
            if(sec==0)      src=x+(size_t)rid[r]*128;
            else if(sec==1) src=x+(size_t)rid[64+r]*128;
            else { int eid=row0+r; if(eid>=Ne) eid=Ne-1; src=e+(size_t)eid*128; }
            uint4 raw=*(const uint4*)(src+half*64+cg*8);
            float* dst=&As[r*68+cg*8];
            dst[0]=b2f((u16)(raw.x&0xffff)); dst[1]=b2f((u16)(raw.x>>16));
            dst[2]=b2f((u16)(raw.y&0xffff)); dst[3]=b2f((u16)(raw.y>>16));
            dst[4]=b2f((u16)(raw.z&0xffff)); dst[5]=b2f((u16)(raw.z>>16));
            dst[6]=b2f((u16)(raw.w&0xffff)); dst[7]=b2f((u16)(raw.w>>16));
        }
        const float* wb=We+((size_t)sec*128+half*64)*128;
        for(int i2=tid;i2<64*128;i2+=256){
            int k=i2>>7,c=i2&127;
            Ws[k*132+c]=wb[(size_t)k*128+c];
        }
        __syncthreads();
#pragma unroll 4
        for(int k0=0;k0<64;k0+=4){
            float4 a[4],bl[4],bh[4];
#pragma unroll
            for(int r=0;r<4;++r) a[r]=*(const float4*)&As[(ty*4+r)*68+k0];
#pragma unroll
            for(int kk=0;kk<4;++kk){
                bl[kk]=*(const float4*)&Ws[(k0+kk)*132+tx*4];
                bh[kk]=*(const float4*)&Ws[(k0+kk)*132+64+tx*4];
            }
#pragma unroll
            for(int r=0;r<4;++r){
                float4 av=a[r];
                acc[r][0]+=av.x*bl[0].x+av.y*bl[1].x+av.z*bl[2].x+av.w*bl[3].x;
                acc[r][1]+=av.x*bl[0].y+av.y*bl[1].y+av.z*bl[2].y+av.w*bl[3].y;
                acc[r][2]+=av.x*bl[0].z+av.y*bl[1].z+av.z*bl[2].z+av.w*bl[3].z;
                acc[r][3]+=av.x*bl[0].w+av.y*bl[1].w+av.z*bl[2].w+av.w*bl[3].w;
                acc[r][4]+=av.x*bh[0].x+av.y*bh[1].x+av.z*bh[2].x+av.w*bh[3].x;
                acc[r][5]+=av.x*bh[0].y+av.y*bh[1].y+av.z*bh[2].y+av.w*bh[3].y;
                acc[r][6]+=av.x*bh[0].z+av.y*bh[1].z+av.z*bh[2].z+av.w*bh[3].z;
                acc[r][7]+=av.x*bh[0].w+av.y*bh[1].w+av.z*bh[2].w+av.w*bh[3].w;
            }
        }
    }
    const int colL=tx*4, colH=64+tx*4;
#pragma unroll
    for(int r=0;r<4;++r){
        int eid=row0+ty*4+r;
        float z[8];
#pragma unroll
        for(int cc=0;cc<4;++cc){
            z[cc]  =acc[r][cc]  +be[colL+cc];
            z[4+cc]=acc[r][4+cc]+be[colH+cc];
        }
        float s=0.f,q=0.f;
#pragma unroll
        for(int c=0;c<8;++c){ s+=z[c]; q+=z[c]*z[c]; }
        for(int m=1;m<16;m<<=1){ s+=__shfl_xor(s,m,64); q+=__shfl_xor(q,m,64); }
        float mean=s*(1.f/128.f), var=q*(1.f/128.f)-mean*mean;
        float rstd=rsqrtf(var+1e-5f);
        if(eid<Ne){
            u16* erow=e+(size_t)eid*128;
#pragma unroll
            for(int cc=0;cc<4;++cc){
                float h=g[colL+cc]*(z[cc]-mean)*rstd+b[colL+cc];
                erow[colL+cc]=f2b(b2f(erow[colL+cc])+silu_f(h));
                h=g[colH+cc]*(z[4+cc]-mean)*rstd+b[colH+cc];
                erow[colH+cc]=f2b(b2f(erow[colH+cc])+silu_f(h));
            }
        }
    }
}

__global__ __launch_bounds__(256)
void bn_stats_k(const u16* __restrict__ h, float* __restrict__ st, int N){
    int t=blockIdx.x*256+threadIdx.x;
    int d=t&127, r0=t>>7, rstride=(gridDim.x*256)>>7;
    float s=0.f,q=0.f;
    for(int r=r0;r<N;r+=rstride){ float v=b2f(h[(size_t)r*128+d]); s+=v; q+=v*v; }
    atomicAdd(&st[d],s); atomicAdd(&st[128+d],q);
}
__global__ __launch_bounds__(256)
void bn_apply_k(u16* __restrict__ h, const float* __restrict__ st,
                const float* __restrict__ g, const float* __restrict__ b, int N){
    int t=blockIdx.x*256+threadIdx.x;
    if(t>=N*128) return;
    int d=t&127;
    float inv=1.f/(float)N;
    float m=st[d]*inv, var=st[128+d]*inv-m*m;
    float v=g[d]*(b2f(h[t])-m)*rsqrtf(var+1e-5f)+b[d];
    h[t]=f2b(silu_f(v));
}
__global__ __launch_bounds__(256)
void pool_k(const u16* __restrict__ o, const int* __restrict__ batch,
            const int* __restrict__ iflag,
            float* __restrict__ pooled, float* __restrict__ cnt, int N, int NG){
    int st=iflag[2];
    int wid=threadIdx.x>>6, lane=threadIdx.x&63;
    int n=blockIdx.x*4+wid; if(n>=N) return;
    int gi=batch[(size_t)n*st]; gi=gi<0?0:(gi>=NG?NG-1:gi);
    atomicAdd(&pooled[(size_t)gi*128+lane],    b2f(o[(size_t)n*128+lane]));
    atomicAdd(&pooled[(size_t)gi*128+64+lane], b2f(o[(size_t)n*128+64+lane]));
    if(lane==0) atomicAdd(&cnt[gi],1.f);
}
__global__ void final_k(const float* __restrict__ pooled, const float* __restrict__ cnt,
                        const float* __restrict__ oW, const float* __restrict__ ob,
                        float* __restrict__ out){
    int gi=blockIdx.x, lane=threadIdx.x;
    float v=pooled[(size_t)gi*128+lane]*oW[lane]
           +pooled[(size_t)gi*128+64+lane]*oW[64+lane];
    for(int m=32;m;m>>=1) v+=__shfl_xor(v,m,64);
    if(lane==0) out[gi]=v/fmaxf(cnt[gi],1.f)+ob[0];
}

template<typename TA>
static inline void gemm(hipStream_t s, const TA* A, int lda, int M, int K,
                        const float* W, const float* bias, u16* C, int act){
    dim3 grid((M+63)/64);
    if(act) gemm_k<TA,1><<<grid,256,0,s>>>(A,lda,M,K,W,bias,C);
    else    gemm_k<TA,0><<<grid,256,0,s>>>(A,lda,M,K,W,bias,C);
}

static inline void build_csr(hipStream_t s, const int* idx, int fi, const int* iflag,
                             int Ne, int Nn, int* off, int* cur, int* list, int* tot){
    int nb=(Nn+SCH-1)/SCH;
    zero_i_k<<<256,256,0,s>>>(cur,Nn);
    hist_k<<<(Ne+255)/256,256,0,s>>>(idx,iflag,fi,cur,Ne,Nn);
    scan1_k<<<nb,256,0,s>>>(cur,tot,Nn);
    scan2_k<<<1,1,0,s>>>(tot,nb);
    scan3_k<<<nb,256,0,s>>>(cur,tot,off,Nn,Ne);
    zero_i_k<<<256,256,0,s>>>(cur,Nn);
    fill_k<<<(Ne+255)/256,256,0,s>>>(idx,iflag,fi,off,cur,list,Ne,Nn);
}

extern "C" void kernel_launch(void* const* d_in, const int* in_sizes, int n_in,
                              void* d_out, int out_size, void* d_ws, size_t ws_size,
                              hipStream_t stream)
{
    const float* x_in =(const float*)d_in[0];
    const float* ea   =(const float*)d_in[1];
    const float* eal  =(const float*)d_in[2];
    const int*   ei   =(const int*)d_in[3];
    const int*   eil  =(const int*)d_in[4];
    const int*   batch=(const int*)d_in[5];
    const float* pre1W=(const float*)d_in[6];  const float* pre1b=(const float*)d_in[7];
    const float* pre2W=(const float*)d_in[8];  const float* pre2b=(const float*)d_in[9];
    const float* pre3W=(const float*)d_in[10]; const float* pre3b=(const float*)d_in[11];
    const float* lWsrc=(const float*)d_in[12]; const float* lbsrc=(const float*)d_in[13];
    const float* lWdst=(const float*)d_in[14]; const float* lbdst=(const float*)d_in[15];
    const float* lWe  =(const float*)d_in[16]; const float* lbe  =(const float*)d_in[17];
    const float* lnxg =(const float*)d_in[18]; const float* lnxb =(const float*)d_in[19];
    const float* lneg =(const float*)d_in[20]; const float* lneb =(const float*)d_in[21];
    const float* aWsrc=(const float*)d_in[22]; const float* absrc=(const float*)d_in[23];
    const float* aWdst=(const float*)d_in[24]; const float* abdst=(const float*)d_in[25];
    const float* aWe  =(const float*)d_in[26]; const float* abe  =(const float*)d_in[27];
    const float* anxg =(const float*)d_in[28]; const float* anxb =(const float*)d_in[29];
    const float* aneg =(const float*)d_in[30]; const float* aneb =(const float*)d_in[31];
    const float* bng  =(const float*)d_in[32]; const float* bnb  =(const float*)d_in[33];
    const float* postW=(const float*)d_in[34]; const float* postb=(const float*)d_in[35];
    const float* outW =(const float*)d_in[36]; const float* outb =(const float*)d_in[37];
    (void)n_in;

    const int N =in_sizes[5];
    const int E =in_sizes[3]/2;
    const int EL=in_sizes[4]/2;
    const int NG=out_size;
    const int CH=(E+1)/2;

    char* base=(char*)d_ws;
    size_t off=0;
    auto alloc=[&](size_t bytes)->char*{
        char* p=base+off; off=(off+bytes+255)&~(size_t)255; return p;
    };
    u16* hNa  =(u16*)alloc((size_t)N*128*2);
    u16* hNb  =(u16*)alloc((size_t)N*128*2);
    u16* hEa  =(u16*)alloc((size_t)E*128*2);
    u16* hEb  =(u16*)alloc((size_t)E*128*2);
    u16* hL   =(u16*)alloc((size_t)EL*128*2);
    u16* P1   =(u16*)alloc((size_t)CH*128*2);
    int* off_l=(int*)alloc((size_t)(E+1)*4);
    int* cur_l=(int*)alloc((size_t)E*4);
    int* list_l=(int*)alloc((size_t)EL*4);
    int* off_a=(int*)alloc((size_t)(N+1)*4);
    int* cur_a=(int*)alloc((size_t)N*4);
    int* list_a=(int*)alloc((size_t)E*4);
    int* tot  =(int*)alloc(4096);
    int* iflag=(int*)alloc(64);
    float* stats =(float*)alloc(256*4);
    float* pooled=(float*)alloc((size_t)NG*128*4);
    float* cnt   =(float*)alloc((size_t)NG*4);
    if(off>ws_size){
        diag_k<<<(NG+255)/256,256,0,stream>>>((float*)d_out,NG,(float)(ws_size>>20)+0.25f);
        return;
    }

    probe_k<<<1,64,0,stream>>>(ei,eil,batch,N,iflag);
    build_csr(stream,eil,1,iflag,EL,E,off_l,cur_l,list_l,tot);
    build_csr(stream,ei, 0,iflag,E, N,off_a,cur_a,list_a,tot);

    gemm(stream,x_in,92,N, 92,pre1W,pre1b,hNa,1);
    gemm(stream,ea,  50,E, 50,pre2W,pre2b,hEa,1);
    gemm(stream,eal, 40,EL,40,pre3W,pre3b,hL, 1);

    u16* hN=hNa; u16* hNalt=hNb;
    u16* hE=hEa; u16* hEalt=hEb;

    for(int l=0;l<NCONV_DEF;++l){
        {
            const float* Wsrc=lWsrc+(size_t)l*128*128; const float* bsrc=lbsrc+l*128;
            const float* Wdst=lWdst+(size_t)l*128*128; const float* bdst=lbdst+l*128;
            const float* We  =lWe  +(size_t)l*384*128; const float* be  =lbe +l*128;
            gemm(stream,hE,128,E,128,Wsrc,bsrc,hEalt,0);
            gemm(stream,hE,128,CH,128,Wdst,bdst,P1,0);
            gather_k<0><<<(E+3)/4,256,0,stream>>>(hE,hEalt,hL,P1,off_l,list_l,
                                                  eil,EL,iflag,1,
                                                  lnxg+l*128,lnxb+l*128,E,0,CH);
            gemm(stream,hE+(size_t)CH*128,128,E-CH,128,Wdst,bdst,P1,0);
            gather_k<1><<<(E+3)/4,256,0,stream>>>(hE,hEalt,hL,P1,off_l,list_l,
                                                  eil,EL,iflag,1,
                                                  lnxg+l*128,lnxb+l*128,E,CH,E);
            edgez_k<<<(EL+63)/64,256,0,stream>>>(hL,hE,eil,EL,iflag,1,
                                                 We,be,lneg+l*128,lneb+l*128,EL,E);
            u16* t=hE; hE=hEalt; hEalt=t;
        }
        {
            const float* Wsrc=aWsrc+(size_t)l*128*128; const float* bsrc=absrc+l*128;
            const float* Wdst=aWdst+(size_t)l*128*128; const float* bdst=abdst+l*128;
            const float* We  =aWe  +(size_t)l*384*128; const float* be  =abe +l*128;
            gemm(stream,hN,128,N,128,Wsrc,bsrc,hNalt,0);
            gemm(stream,hN,128,N,128,Wdst,bdst,P1,0);
            gather_k<1><<<(N+3)/4,256,0,stream>>>(hN,hNalt,hE,P1,off_a,list_a,
                                                  ei,E,iflag,0,
                                                  anxg+l*128,anxb+l*128,N,0,N);
            edgez_k<<<(E+63)/64,256,0,stream>>>(hE,hN,ei,E,iflag,0,
                                                We,be,aneg+l*128,aneb+l*128,E,N);
            u16* t=hN; hN=hNalt; hNalt=t;
        }
    }

    zero_f_k<<<64,256,0,stream>>>(stats,256);
    zero_f_k<<<64,256,0,stream>>>(pooled,(long)NG*128);
    zero_f_k<<<1,256,0,stream>>>(cnt,NG);
    bn_stats_k<<<256,256,0,stream>>>(hN,stats,N);
    bn_apply_k<<<(N*128+255)/256,256,0,stream>>>(hN,stats,bng,bnb,N);

    gemm(stream,hN,128,N,128,postW,postb,P1,1);

    pool_k<<<(N+3)/4,256,0,stream>>>(P1,batch,iflag,pooled,cnt,N,NG);
    final_k<<<NG,64,0,stream>>>(pooled,cnt,outW,outb,(float*)d_out);
}

// Round 4
// 5202.581 us; speedup vs baseline: 2.1878x; 2.1878x over previous
//
#include <hip/hip_runtime.h>

#define NCONV_DEF 4
#define SCH 1024

typedef unsigned short u16;
typedef __attribute__((ext_vector_type(8))) short s8v;      // MFMA bf16 A/B frag
typedef __attribute__((ext_vector_type(4))) float f4v;      // MFMA C/D frag
typedef __attribute__((ext_vector_type(8))) unsigned short u16x8;

__device__ __forceinline__ float sigm_f(float x){ return 1.f/(1.f+__expf(-x)); }
__device__ __forceinline__ float silu_f(float x){ return x/(1.f+__expf(-x)); }
__device__ __forceinline__ float b2f(u16 h){ union{unsigned u; float f;} v; v.u=(unsigned)h<<16; return v.f; }
__device__ __forceinline__ u16 f2b(float f){ union{float f; unsigned u;} v; v.f=f; unsigned r=v.u+0x7fffu+((v.u>>16)&1u); return (u16)(r>>16); }
__device__ __forceinline__ float ldA(const float* p, size_t i){ return p[i]; }
__device__ __forceinline__ float ldA(const u16* p, size_t i){ return b2f(p[i]); }

__global__ __launch_bounds__(256) void zero_f_k(float* p, long n){
    long i=(long)blockIdx.x*256+threadIdx.x, st=(long)gridDim.x*256;
    for(;i<n;i+=st) p[i]=0.f;
}
__global__ __launch_bounds__(256) void zero_i_k(int* p, long n){
    long i=(long)blockIdx.x*256+threadIdx.x, st=(long)gridDim.x*256;
    for(;i<n;i+=st) p[i]=0;
}
__global__ void diag_k(float* out, int n, float v){
    int i=blockIdx.x*256+threadIdx.x; if(i<n) out[i]=v;
}
__global__ void probe_k(const int* ei, const int* eil, const int* batch, int nb, int* flag){
    if(threadIdx.x||blockIdx.x) return;
    int a=2,b=2,c=2;
    for(int k=0;k<64;k++){ if(ei[2*k+1]!=0) a=1; if(eil[2*k+1]!=0) b=1; }
    int base=nb-128;
    for(int k=0;k<64;k++){ if(batch[base+2*k+1]!=0) c=1; }
    flag[0]=a; flag[1]=b; flag[2]=c;
}

// ---------------- CSR build ----------------------------------------------------
__global__ __launch_bounds__(256)
void hist_k(const int* __restrict__ idx, const int* __restrict__ iflag, int fi,
            int* __restrict__ cnt, int Ne, int Nn){
    int e=blockIdx.x*256+threadIdx.x; if(e>=Ne) return;
    int st=iflag[fi];
    int i=idx[(size_t)e*st]; i=i<0?0:(i>=Nn?Nn-1:i);
    atomicAdd(&cnt[i],1);
}
__global__ __launch_bounds__(256)
void scan1_k(const int* cnt, int* tot, int n){
    __shared__ int sh[256];
    int base=blockIdx.x*SCH, s=0;
    for(int t=threadIdx.x;t<SCH;t+=256){ int i=base+t; s+=(i<n)?cnt[i]:0; }
    sh[threadIdx.x]=s; __syncthreads();
    for(int o=128;o;o>>=1){ if(threadIdx.x<o) sh[threadIdx.x]+=sh[threadIdx.x+o]; __syncthreads(); }
    if(threadIdx.x==0) tot[blockIdx.x]=sh[0];
}
__global__ void scan2_k(int* tot, int nb){
    if(threadIdx.x==0&&blockIdx.x==0){ int acc=0; for(int i=0;i<nb;i++){int v=tot[i]; tot[i]=acc; acc+=v;} }
}
__global__ __launch_bounds__(256)
void scan3_k(const int* cnt, const int* tot, int* off, int n, int total){
    __shared__ int sh[256];
    int b=blockIdx.x, t4=b*SCH+threadIdx.x*4;
    int v0=(t4+0<n)?cnt[t4+0]:0, v1=(t4+1<n)?cnt[t4+1]:0;
    int v2=(t4+2<n)?cnt[t4+2]:0, v3=(t4+3<n)?cnt[t4+3]:0;
    int ls=v0+v1+v2+v3;
    sh[threadIdx.x]=ls; __syncthreads();
    for(int o=1;o<256;o<<=1){
        int val=(threadIdx.x>=o)?sh[threadIdx.x-o]:0; __syncthreads();
        sh[threadIdx.x]+=val; __syncthreads();
    }
    int excl=sh[threadIdx.x]-ls+tot[b];
    if(t4+0<n) off[t4+0]=excl;
    if(t4+1<n) off[t4+1]=excl+v0;
    if(t4+2<n) off[t4+2]=excl+v0+v1;
    if(t4+3<n) off[t4+3]=excl+v0+v1+v2;
    if(b==(int)gridDim.x-1&&threadIdx.x==255) off[n]=total;
}
__global__ __launch_bounds__(256)
void fill_k(const int* __restrict__ idx, const int* __restrict__ iflag, int fi,
            const int* __restrict__ off, int* __restrict__ cur, int* __restrict__ list,
            int Ne, int Nn){
    int e=blockIdx.x*256+threadIdx.x; if(e>=Ne) return;
    int st=iflag[fi];
    int i=idx[(size_t)e*st]; i=i<0?0:(i>=Nn?Nn-1:i);
    int pos=off[i]+atomicAdd(&cur[i],1);
    list[pos]=e;
}

// ---------------- weight pack: W[K][128] f32 -> Wp[128][Kp] bf16 ---------------
__global__ __launch_bounds__(256)
void pack_w_k(const float* __restrict__ W, u16* __restrict__ Wp, int K, int Kp){
    int i=blockIdx.x*256+threadIdx.x;
    if(i>=128*Kp) return;
    int n=i/Kp, k=i-n*Kp;
    Wp[i] = (k<K) ? f2b(W[(size_t)k*128+n]) : (u16)0;
}

// ---------------- MFMA GEMM: C[M,128] = A[M,K] @ W[K,128] (+bias)(+silu) -------
// 64-row tile, 4 waves (16 rows each), N=128 as 8 col-tiles of 16. bf16 MFMA.
template<typename TA, int ACT>
__global__ __launch_bounds__(256)
void gemm_k(const TA* __restrict__ A, int lda, int M, int K, int Kp,
            const u16* __restrict__ Wp, const float* __restrict__ bias,
            u16* __restrict__ C)
{
    __shared__ __align__(16) u16 As[64*72];
    __shared__ __align__(16) u16 Bs[128*72];
    const int tid=threadIdx.x, row0=blockIdx.x*64;
    const int w=tid>>6, l=tid&63, lr=l&15, kg=l>>4;
    f4v zz={0.f,0.f,0.f,0.f};
    f4v acc[8];
#pragma unroll
    for(int i=0;i<8;++i) acc[i]=zz;

    for(int kt=0;kt<Kp;kt+=64){
        // stage A tile [64][64] bf16
        {
            int r=tid>>2, c0=(tid&3)*16;
            int gr=row0+r;
            bool vec=false;
            if constexpr (sizeof(TA)==2) vec=((K&63)==0);
            if(vec){
                const u16* src=(const u16*)(const void*)A+(size_t)gr*lda+kt+c0;
                u16x8 v0={0,0,0,0,0,0,0,0}, v1={0,0,0,0,0,0,0,0};
                if(gr<M){ v0=*(const u16x8*)src; v1=*(const u16x8*)(src+8); }
                *(u16x8*)&As[r*72+c0]=v0;
                *(u16x8*)&As[r*72+c0+8]=v1;
            } else {
                for(int c=c0;c<c0+16;++c){
                    int k=kt+c;
                    float v=(gr<M&&k<K)?ldA(A,(size_t)gr*lda+k):0.f;
                    As[r*72+c]=f2b(v);
                }
            }
        }
        // stage B tile [128][64] bf16 from packed Wp[128][Kp]
        {
            int n=tid>>1, k0=(tid&1)*32;
            const u16* src=Wp+(size_t)n*Kp+kt+k0;
            *(u16x8*)&Bs[n*72+k0]   =*(const u16x8*)(src);
            *(u16x8*)&Bs[n*72+k0+8] =*(const u16x8*)(src+8);
            *(u16x8*)&Bs[n*72+k0+16]=*(const u16x8*)(src+16);
            *(u16x8*)&Bs[n*72+k0+24]=*(const u16x8*)(src+24);
        }
        __syncthreads();
        const int arow=w*16+lr;
#pragma unroll
        for(int kk=0;kk<64;kk+=32){
            s8v a=*(const s8v*)&As[arow*72+kk+kg*8];
#pragma unroll
            for(int ct=0;ct<8;++ct){
                s8v bfr=*(const s8v*)&Bs[(ct*16+lr)*72+kk+kg*8];
                acc[ct]=__builtin_amdgcn_mfma_f32_16x16x32_bf16(a,bfr,acc[ct],0,0,0);
            }
        }
        __syncthreads();
    }
#pragma unroll
    for(int reg=0;reg<4;++reg){
        int gr=row0+w*16+kg*4+reg;
        if(gr>=M) continue;
        u16* crow=C+(size_t)gr*128;
#pragma unroll
        for(int ct=0;ct<8;++ct){
            int col=ct*16+lr;
            float v=acc[ct][reg];
            if(bias) v+=bias[col];
            if(ACT) v=silu_f(v);
            crow[col]=f2b(v);
        }
    }
}

// ---------------- node gather: esum + gated messages + node update -------------
template<int FINAL>
__global__ __launch_bounds__(256)
void gather_k(const u16* __restrict__ x, u16* __restrict__ xnew,
              const u16* __restrict__ e, const u16* __restrict__ P1,
              const int* __restrict__ off, const int* __restrict__ list,
              const int* __restrict__ idx, long joff,
              const int* __restrict__ iflag, int fi,
              const float* __restrict__ g, const float* __restrict__ b,
              int Nn, int c0, int c1)
{
    int st=iflag[fi];
    int wid=threadIdx.x>>6, lane=threadIdx.x&63;
    int n=blockIdx.x*4+wid; if(n>=Nn) return;
    int beg=off[n], end=off[n+1];
    float es0=0.f, es1=0.f;
    for(int k=beg;k<end;++k){
        int eid=list[k];
        const u16* er=e+(size_t)eid*128;
        es0+=sigm_f(b2f(er[lane]));
        es1+=sigm_f(b2f(er[64+lane]));
    }
    float r0=1.f/(es0+1e-5f), r1=1.f/(es1+1e-5f);
    float a0=0.f, a1=0.f;
    for(int k=beg;k<end;++k){
        int eid=list[k];
        int j=idx[((size_t)joff+eid)*st]; j=j<0?0:(j>=Nn?Nn-1:j);
        if(j<c0||j>=c1) continue;
        const u16* er=e+(size_t)eid*128;
        const u16* pr=P1+(size_t)(j-c0)*128;
        a0+=sigm_f(b2f(er[lane]))*r0*b2f(pr[lane]);
        a1+=sigm_f(b2f(er[64+lane]))*r1*b2f(pr[64+lane]);
    }
    size_t ro=(size_t)n*128;
    float z0=b2f(xnew[ro+lane])+a0;
    float z1=b2f(xnew[ro+64+lane])+a1;
    if(!FINAL){
        xnew[ro+lane]=f2b(z0); xnew[ro+64+lane]=f2b(z1);
    } else {
        float s=z0+z1, q=z0*z0+z1*z1;
        for(int m=32;m;m>>=1){ s+=__shfl_xor(s,m,64); q+=__shfl_xor(q,m,64); }
        float mean=s*(1.f/128.f), var=q*(1.f/128.f)-mean*mean;
        float rstd=rsqrtf(var+1e-5f);
        float h0=g[lane]*(z0-mean)*rstd+b[lane];
        float h1=g[64+lane]*(z1-mean)*rstd+b[64+lane];
        xnew[ro+lane]   =f2b(b2f(x[ro+lane])   +silu_f(h0));
        xnew[ro+64+lane]=f2b(b2f(x[ro+64+lane])+silu_f(h1));
    }
}

// ---------------- fused edge update (MFMA), in place on e ----------------------
// e += silu(LN([x_i|x_j|e] @ We + be)); 64 edges/block, We packed [128][384] bf16
__global__ __launch_bounds__(256)
void edgez_k(u16* __restrict__ e, const u16* __restrict__ x,
             const int* __restrict__ idx, long joff,
             const int* __restrict__ iflag, int fi,
             const u16* __restrict__ Wep, const float* __restrict__ be,
             const float* __restrict__ g, const float* __restrict__ b,
             int Ne, int Nn)
{
    __shared__ __align__(16) u16 As[64*72];
    __shared__ __align__(16) u16 Bs[128*72];
    __shared__ int rid[128];
    const int tid=threadIdx.x, row0=blockIdx.x*64;
    const int w=tid>>6, l=tid&63, lr=l&15, kg=l>>4;
    int st=iflag[fi];
    if(tid<128){
        int r=tid&63, eid=row0+r; if(eid>=Ne) eid=Ne-1;
        long elem=(tid<64)?(long)eid:(joff+eid);
        int v=idx[(size_t)elem*st]; v=v<0?0:(v>=Nn?Nn-1:v);
        rid[tid]=v;
    }
    __syncthreads();
    f4v zz={0.f,0.f,0.f,0.f};
    f4v acc[8];
#pragma unroll
    for(int i=0;i<8;++i) acc[i]=zz;

    for(int s=0;s<6;++s){
        const int sec=s>>1, half=s&1;
        // stage A: 64 gathered rows, 64 bf16 each
        {
            int r=tid>>2, c0=(tid&3)*16;
            const u16* src;
            if(sec==0)      src=x+(size_t)rid[r]*128;
            else if(sec==1) src=x+(size_t)rid[64+r]*128;
            else { int eid=row0+r; if(eid>=Ne) eid=Ne-1; src=e+(size_t)eid*128; }
            src+=half*64+c0;
            *(u16x8*)&As[r*72+c0]  =*(const u16x8*)src;
            *(u16x8*)&As[r*72+c0+8]=*(const u16x8*)(src+8);
        }
        // stage B: Wep k-slice [128][64]
        {
            int n=tid>>1, k0=(tid&1)*32;
            const u16* src=Wep+(size_t)n*384+s*64+k0;
            *(u16x8*)&Bs[n*72+k0]   =*(const u16x8*)(src);
            *(u16x8*)&Bs[n*72+k0+8] =*(const u16x8*)(src+8);
            *(u16x8*)&Bs[n*72+k0+16]=*(const u16x8*)(src+16);
            *(u16x8*)&Bs[n*72+k0+24]=*(const u16x8*)(src+24);
        }
        __syncthreads();
        const int arow=w*16+lr;
#pragma unroll
        for(int kk=0;kk<64;kk+=32){
            s8v a=*(const s8v*)&As[arow*72+kk+kg*8];
#pragma unroll
            for(int ct=0;ct<8;++ct){
                s8v bfr=*(const s8v*)&Bs[(ct*16+lr)*72+kk+kg*8];
                acc[ct]=__builtin_amdgcn_mfma_f32_16x16x32_bf16(a,bfr,acc[ct],0,0,0);
            }
        }
        __syncthreads();
    }
    // epilogue: +be, row-LN (rows spread over 16-lane groups), silu, residual
    float sum[4]={0.f,0.f,0.f,0.f}, sq[4]={0.f,0.f,0.f,0.f};
#pragma unroll
    for(int ct=0;ct<8;++ct){
        float bev=be[ct*16+lr];
#pragma unroll
        for(int reg=0;reg<4;++reg){
            float v=acc[ct][reg]+bev;
            acc[ct][reg]=v;
            sum[reg]+=v; sq[reg]+=v*v;
        }
    }
#pragma unroll
    for(int m=1;m<16;m<<=1){
#pragma unroll
        for(int reg=0;reg<4;++reg){
            sum[reg]+=__shfl_xor(sum[reg],m,64);
            sq[reg] +=__shfl_xor(sq[reg], m,64);
        }
    }
    float mean[4], rstd[4];
#pragma unroll
    for(int reg=0;reg<4;++reg){
        mean[reg]=sum[reg]*(1.f/128.f);
        float var=sq[reg]*(1.f/128.f)-mean[reg]*mean[reg];
        rstd[reg]=rsqrtf(var+1e-5f);
    }
#pragma unroll
    for(int ct=0;ct<8;++ct){
        int col=ct*16+lr;
        float gv=g[col], bv=b[col];
#pragma unroll
        for(int reg=0;reg<4;++reg){
            int eid=row0+w*16+kg*4+reg;
            if(eid<Ne){
                float h=gv*(acc[ct][reg]-mean[reg])*rstd[reg]+bv;
                u16* p=e+(size_t)eid*128+col;
                *p=f2b(b2f(*p)+silu_f(h));
            }
        }
    }
}

// ---------------- BatchNorm / pool / head --------------------------------------
__global__ __launch_bounds__(256)
void bn_stats_k(const u16* __restrict__ h, float* __restrict__ st, int N){
    int t=blockIdx.x*256+threadIdx.x;
    int d=t&127, r0=t>>7, rstride=(gridDim.x*256)>>7;
    float s=0.f,q=0.f;
    for(int r=r0;r<N;r+=rstride){ float v=b2f(h[(size_t)r*128+d]); s+=v; q+=v*v; }
    atomicAdd(&st[d],s); atomicAdd(&st[128+d],q);
}
__global__ __launch_bounds__(256)
void bn_apply_k(u16* __restrict__ h, const float* __restrict__ st,
                const float* __restrict__ g, const float* __restrict__ b, int N){
    int t=blockIdx.x*256+threadIdx.x;
    if(t>=N*128) return;
    int d=t&127;
    float inv=1.f/(float)N;
    float m=st[d]*inv, var=st[128+d]*inv-m*m;
    float v=g[d]*(b2f(h[t])-m)*rsqrtf(var+1e-5f)+b[d];
    h[t]=f2b(silu_f(v));
}
__global__ __launch_bounds__(256)
void pool_k(const u16* __restrict__ o, const int* __restrict__ batch,
            const int* __restrict__ iflag,
            float* __restrict__ pooled, float* __restrict__ cnt, int N, int NG){
    int st=iflag[2];
    int wid=threadIdx.x>>6, lane=threadIdx.x&63;
    int n=blockIdx.x*4+wid; if(n>=N) return;
    int gi=batch[(size_t)n*st]; gi=gi<0?0:(gi>=NG?NG-1:gi);
    atomicAdd(&pooled[(size_t)gi*128+lane],    b2f(o[(size_t)n*128+lane]));
    atomicAdd(&pooled[(size_t)gi*128+64+lane], b2f(o[(size_t)n*128+64+lane]));
    if(lane==0) atomicAdd(&cnt[gi],1.f);
}
__global__ void final_k(const float* __restrict__ pooled, const float* __restrict__ cnt,
                        const float* __restrict__ oW, const float* __restrict__ ob,
                        float* __restrict__ out){
    int gi=blockIdx.x, lane=threadIdx.x;
    float v=pooled[(size_t)gi*128+lane]*oW[lane]
           +pooled[(size_t)gi*128+64+lane]*oW[64+lane];
    for(int m=32;m;m>>=1) v+=__shfl_xor(v,m,64);
    if(lane==0) out[gi]=v/fmaxf(cnt[gi],1.f)+ob[0];
}

// -------------------------------------------------------------------------------
template<typename TA>
static inline void gemm(hipStream_t s, const TA* A, int lda, int M, int K, int Kp,
                        const u16* Wp, const float* bias, u16* C, int act){
    dim3 grid((M+63)/64);
    if(act) gemm_k<TA,1><<<grid,256,0,s>>>(A,lda,M,K,Kp,Wp,bias,C);
    else    gemm_k<TA,0><<<grid,256,0,s>>>(A,lda,M,K,Kp,Wp,bias,C);
}

static inline void build_csr(hipStream_t s, const int* idx, int fi, const int* iflag,
                             int Ne, int Nn, int* off, int* cur, int* list, int* tot){
    int nb=(Nn+SCH-1)/SCH;
    zero_i_k<<<256,256,0,s>>>(cur,Nn);
    hist_k<<<(Ne+255)/256,256,0,s>>>(idx,iflag,fi,cur,Ne,Nn);
    scan1_k<<<nb,256,0,s>>>(cur,tot,Nn);
    scan2_k<<<1,1,0,s>>>(tot,nb);
    scan3_k<<<nb,256,0,s>>>(cur,tot,off,Nn,Ne);
    zero_i_k<<<256,256,0,s>>>(cur,Nn);
    fill_k<<<(Ne+255)/256,256,0,s>>>(idx,iflag,fi,off,cur,list,Ne,Nn);
}

static inline void pack_w(hipStream_t s, const float* W, u16* Wp, int K, int Kp){
    pack_w_k<<<(128*Kp+255)/256,256,0,s>>>(W,Wp,K,Kp);
}

extern "C" void kernel_launch(void* const* d_in, const int* in_sizes, int n_in,
                              void* d_out, int out_size, void* d_ws, size_t ws_size,
                              hipStream_t stream)
{
    const float* x_in =(const float*)d_in[0];
    const float* ea   =(const float*)d_in[1];
    const float* eal  =(const float*)d_in[2];
    const int*   ei   =(const int*)d_in[3];
    const int*   eil  =(const int*)d_in[4];
    const int*   batch=(const int*)d_in[5];
    const float* pre1W=(const float*)d_in[6];  const float* pre1b=(const float*)d_in[7];
    const float* pre2W=(const float*)d_in[8];  const float* pre2b=(const float*)d_in[9];
    const float* pre3W=(const float*)d_in[10]; const float* pre3b=(const float*)d_in[11];
    const float* lWsrc=(const float*)d_in[12]; const float* lbsrc=(const float*)d_in[13];
    const float* lWdst=(const float*)d_in[14]; const float* lbdst=(const float*)d_in[15];
    const float* lWe  =(const float*)d_in[16]; const float* lbe  =(const float*)d_in[17];
    const float* lnxg =(const float*)d_in[18]; const float* lnxb =(const float*)d_in[19];
    const float* lneg =(const float*)d_in[20]; const float* lneb =(const float*)d_in[21];
    const float* aWsrc=(const float*)d_in[22]; const float* absrc=(const float*)d_in[23];
    const float* aWdst=(const float*)d_in[24]; const float* abdst=(const float*)d_in[25];
    const float* aWe  =(const float*)d_in[26]; const float* abe  =(const float*)d_in[27];
    const float* anxg =(const float*)d_in[28]; const float* anxb =(const float*)d_in[29];
    const float* aneg =(const float*)d_in[30]; const float* aneb =(const float*)d_in[31];
    const float* bng  =(const float*)d_in[32]; const float* bnb  =(const float*)d_in[33];
    const float* postW=(const float*)d_in[34]; const float* postb=(const float*)d_in[35];
    const float* outW =(const float*)d_in[36]; const float* outb =(const float*)d_in[37];
    (void)n_in;

    const int N =in_sizes[5];
    const int E =in_sizes[3]/2;
    const int EL=in_sizes[4]/2;
    const int NG=out_size;
    const int CH=(E+1)/2;

    char* base=(char*)d_ws;
    size_t off=0;
    auto alloc=[&](size_t bytes)->char*{
        char* p=base+off; off=(off+bytes+255)&~(size_t)255; return p;
    };
    u16* hNa  =(u16*)alloc((size_t)N*128*2);
    u16* hNb  =(u16*)alloc((size_t)N*128*2);
    u16* hEa  =(u16*)alloc((size_t)E*128*2);
    u16* hEb  =(u16*)alloc((size_t)E*128*2);
    u16* hL   =(u16*)alloc((size_t)EL*128*2);
    u16* P1   =(u16*)alloc((size_t)CH*128*2);
    int* off_l=(int*)alloc((size_t)(E+1)*4);
    int* cur_l=(int*)alloc((size_t)E*4);
    int* list_l=(int*)alloc((size_t)EL*4);
    int* off_a=(int*)alloc((size_t)(N+1)*4);
    int* cur_a=(int*)alloc((size_t)N*4);
    int* list_a=(int*)alloc((size_t)E*4);
    int* tot  =(int*)alloc(4096);
    int* iflag=(int*)alloc(64);
    float* stats =(float*)alloc(256*4);
    float* pooled=(float*)alloc((size_t)NG*128*4);
    float* cnt   =(float*)alloc((size_t)NG*4);
    // packed weights (bf16, [128 n][Kp k])
    u16* pre1p=(u16*)alloc(128*128*2);
    u16* pre2p=(u16*)alloc(128*64*2);
    u16* pre3p=(u16*)alloc(128*64*2);
    u16* postp=(u16*)alloc(128*128*2);
    u16 *lsrcp[4],*ldstp[4],*lWep[4],*asrcp[4],*adstp[4],*aWep[4];
    for(int i=0;i<4;i++){
        lsrcp[i]=(u16*)alloc(128*128*2);
        ldstp[i]=(u16*)alloc(128*128*2);
        lWep[i] =(u16*)alloc(128*384*2);
        asrcp[i]=(u16*)alloc(128*128*2);
        adstp[i]=(u16*)alloc(128*128*2);
        aWep[i] =(u16*)alloc(128*384*2);
    }
    if(off>ws_size){
        diag_k<<<(NG+255)/256,256,0,stream>>>((float*)d_out,NG,(float)(ws_size>>20)+0.25f);
        return;
    }

    probe_k<<<1,64,0,stream>>>(ei,eil,batch,N,iflag);
    build_csr(stream,eil,1,iflag,EL,E,off_l,cur_l,list_l,tot);
    build_csr(stream,ei, 0,iflag,E, N,off_a,cur_a,list_a,tot);

    // pack all weights once (deterministic each launch)
    pack_w(stream,pre1W,pre1p,92,128);
    pack_w(stream,pre2W,pre2p,50,64);
    pack_w(stream,pre3W,pre3p,40,64);
    pack_w(stream,postW,postp,128,128);
    for(int i=0;i<4;i++){
        pack_w(stream,lWsrc+(size_t)i*128*128,lsrcp[i],128,128);
        pack_w(stream,lWdst+(size_t)i*128*128,ldstp[i],128,128);
        pack_w(stream,lWe  +(size_t)i*384*128,lWep[i],384,384);
        pack_w(stream,aWsrc+(size_t)i*128*128,asrcp[i],128,128);
        pack_w(stream,aWdst+(size_t)i*128*128,adstp[i],128,128);
        pack_w(stream,aWe  +(size_t)i*384*128,aWep[i],384,384);
    }

    gemm(stream,x_in,92,N, 92,128,pre1p,pre1b,hNa,1);
    gemm(stream,ea,  50,E, 50, 64,pre2p,pre2b,hEa,1);
    gemm(stream,eal, 40,EL,40, 64,pre3p,pre3b,hL, 1);

    u16* hN=hNa; u16* hNalt=hNb;
    u16* hE=hEa; u16* hEalt=hEb;

    for(int l=0;l<NCONV_DEF;++l){
        {   // line conv: nodes=hE (E), edges=hL (EL)
            gemm(stream,hE,128,E,128,128,lsrcp[l],lbsrc+l*128,hEalt,0);
            gemm(stream,hE,128,CH,128,128,ldstp[l],lbdst+l*128,P1,0);
            gather_k<0><<<(E+3)/4,256,0,stream>>>(hE,hEalt,hL,P1,off_l,list_l,
                                                  eil,EL,iflag,1,
                                                  lnxg+l*128,lnxb+l*128,E,0,CH);
            gemm(stream,hE+(size_t)CH*128,128,E-CH,128,128,ldstp[l],lbdst+l*128,P1,0);
            gather_k<1><<<(E+3)/4,256,0,stream>>>(hE,hEalt,hL,P1,off_l,list_l,
                                                  eil,EL,iflag,1,
                                                  lnxg+l*128,lnxb+l*128,E,CH,E);
            edgez_k<<<(EL+63)/64,256,0,stream>>>(hL,hE,eil,EL,iflag,1,
                                                 lWep[l],lbe+l*128,lneg+l*128,lneb+l*128,EL,E);
            u16* t=hE; hE=hEalt; hEalt=t;
        }
        {   // atom conv: nodes=hN (N), edges=hE (E)
            gemm(stream,hN,128,N,128,128,asrcp[l],absrc+l*128,hNalt,0);
            gemm(stream,hN,128,N,128,128,adstp[l],abdst+l*128,P1,0);
            gather_k<1><<<(N+3)/4,256,0,stream>>>(hN,hNalt,hE,P1,off_a,list_a,
                                                  ei,E,iflag,0,
                                                  anxg+l*128,anxb+l*128,N,0,N);
            edgez_k<<<(E+63)/64,256,0,stream>>>(hE,hN,ei,E,iflag,0,
                                                aWep[l],abe+l*128,aneg+l*128,aneb+l*128,E,N);
            u16* t=hN; hN=hNalt; hNalt=t;
        }
    }

    zero_f_k<<<64,256,0,stream>>>(stats,256);
    zero_f_k<<<64,256,0,stream>>>(pooled,(long)NG*128);
    zero_f_k<<<1,256,0,stream>>>(cnt,NG);
    bn_stats_k<<<256,256,0,stream>>>(hN,stats,N);
    bn_apply_k<<<(N*128+255)/256,256,0,stream>>>(hN,stats,bng,bnb,N);

    gemm(stream,hN,128,N,128,128,postp,postb,P1,1);

    pool_k<<<(N+3)/4,256,0,stream>>>(P1,batch,iflag,pooled,cnt,N,NG);
    final_k<<<NG,64,0,stream>>>(pooled,cnt,outW,outb,(float*)d_out);
}

// Round 5
// 4433.242 us; speedup vs baseline: 2.5675x; 1.1735x over previous
//
#include <hip/hip_runtime.h>

#define NCONV_DEF 4
#define SCH 1024

typedef unsigned short u16;
typedef __attribute__((ext_vector_type(8))) short s8v;      // MFMA bf16 A/B frag
typedef __attribute__((ext_vector_type(4))) float f4v;      // MFMA C/D frag
typedef __attribute__((ext_vector_type(8))) unsigned short u16x8;

__device__ __forceinline__ float sigm_f(float x){ return 1.f/(1.f+__expf(-x)); }
__device__ __forceinline__ float silu_f(float x){ return x/(1.f+__expf(-x)); }
__device__ __forceinline__ float b2f(u16 h){ union{unsigned u; float f;} v; v.u=(unsigned)h<<16; return v.f; }
__device__ __forceinline__ u16 f2b(float f){ union{float f; unsigned u;} v; v.f=f; unsigned r=v.u+0x7fffu+((v.u>>16)&1u); return (u16)(r>>16); }
__device__ __forceinline__ float ldA(const float* p, size_t i){ return p[i]; }
__device__ __forceinline__ float ldA(const u16* p, size_t i){ return b2f(p[i]); }

__global__ __launch_bounds__(256) void zero_f_k(float* p, long n){
    long i=(long)blockIdx.x*256+threadIdx.x, st=(long)gridDim.x*256;
    for(;i<n;i+=st) p[i]=0.f;
}
__global__ __launch_bounds__(256) void zero_i_k(int* p, long n){
    long i=(long)blockIdx.x*256+threadIdx.x, st=(long)gridDim.x*256;
    for(;i<n;i+=st) p[i]=0;
}
__global__ void diag_k(float* out, int n, float v){
    int i=blockIdx.x*256+threadIdx.x; if(i<n) out[i]=v;
}
__global__ void probe_k(const int* ei, const int* eil, const int* batch, int nb, int* flag){
    if(threadIdx.x||blockIdx.x) return;
    int a=2,b=2,c=2;
    for(int k=0;k<64;k++){ if(ei[2*k+1]!=0) a=1; if(eil[2*k+1]!=0) b=1; }
    int base=nb-128;
    for(int k=0;k<64;k++){ if(batch[base+2*k+1]!=0) c=1; }
    flag[0]=a; flag[1]=b; flag[2]=c;
}

// ---------------- CSR build ----------------------------------------------------
__global__ __launch_bounds__(256)
void hist_k(const int* __restrict__ idx, const int* __restrict__ iflag, int fi,
            int* __restrict__ cnt, int Ne, int Nn){
    int e=blockIdx.x*256+threadIdx.x; if(e>=Ne) return;
    int st=iflag[fi];
    int i=idx[(size_t)e*st]; i=i<0?0:(i>=Nn?Nn-1:i);
    atomicAdd(&cnt[i],1);
}
__global__ __launch_bounds__(256)
void scan1_k(const int* cnt, int* tot, int n){
    __shared__ int sh[256];
    int base=blockIdx.x*SCH, s=0;
    for(int t=threadIdx.x;t<SCH;t+=256){ int i=base+t; s+=(i<n)?cnt[i]:0; }
    sh[threadIdx.x]=s; __syncthreads();
    for(int o=128;o;o>>=1){ if(threadIdx.x<o) sh[threadIdx.x]+=sh[threadIdx.x+o]; __syncthreads(); }
    if(threadIdx.x==0) tot[blockIdx.x]=sh[0];
}
__global__ void scan2_k(int* tot, int nb){
    if(threadIdx.x==0&&blockIdx.x==0){ int acc=0; for(int i=0;i<nb;i++){int v=tot[i]; tot[i]=acc; acc+=v;} }
}
__global__ __launch_bounds__(256)
void scan3_k(const int* cnt, const int* tot, int* off, int n, int total){
    __shared__ int sh[256];
    int b=blockIdx.x, t4=b*SCH+threadIdx.x*4;
    int v0=(t4+0<n)?cnt[t4+0]:0, v1=(t4+1<n)?cnt[t4+1]:0;
    int v2=(t4+2<n)?cnt[t4+2]:0, v3=(t4+3<n)?cnt[t4+3]:0;
    int ls=v0+v1+v2+v3;
    sh[threadIdx.x]=ls; __syncthreads();
    for(int o=1;o<256;o<<=1){
        int val=(threadIdx.x>=o)?sh[threadIdx.x-o]:0; __syncthreads();
        sh[threadIdx.x]+=val; __syncthreads();
    }
    int excl=sh[threadIdx.x]-ls+tot[b];
    if(t4+0<n) off[t4+0]=excl;
    if(t4+1<n) off[t4+1]=excl+v0;
    if(t4+2<n) off[t4+2]=excl+v0+v1;
    if(t4+3<n) off[t4+3]=excl+v0+v1+v2;
    if(b==(int)gridDim.x-1&&threadIdx.x==255) off[n]=total;
}
__global__ __launch_bounds__(256)
void fill_k(const int* __restrict__ idx, const int* __restrict__ iflag, int fi,
            const int* __restrict__ off, int* __restrict__ cur, int* __restrict__ list,
            int Ne, int Nn){
    int e=blockIdx.x*256+threadIdx.x; if(e>=Ne) return;
    int st=iflag[fi];
    int i=idx[(size_t)e*st]; i=i<0?0:(i>=Nn?Nn-1:i);
    int pos=off[i]+atomicAdd(&cur[i],1);
    list[pos]=e;
}

// ---------------- weight pack: W[K][128] f32 -> Wp[128][Kp] bf16 ---------------
__global__ __launch_bounds__(256)
void pack_w_k(const float* __restrict__ W, u16* __restrict__ Wp, int K, int Kp){
    int i=blockIdx.x*256+threadIdx.x;
    if(i>=128*Kp) return;
    int n=i/Kp, k=i-n*Kp;
    Wp[i] = (k<K) ? f2b(W[(size_t)k*128+n]) : (u16)0;
}

// ---------------- MFMA GEMM: C[M,128] = A[M,K] @ W[K,128] (+bias)(+silu) -------
template<typename TA, int ACT>
__global__ __launch_bounds__(256)
void gemm_k(const TA* __restrict__ A, int lda, int M, int K, int Kp,
            const u16* __restrict__ Wp, const float* __restrict__ bias,
            u16* __restrict__ C)
{
    __shared__ __align__(16) u16 As[64*72];
    __shared__ __align__(16) u16 Bs[128*72];
    const int tid=threadIdx.x, row0=blockIdx.x*64;
    const int w=tid>>6, l=tid&63, lr=l&15, kg=l>>4;
    f4v zz={0.f,0.f,0.f,0.f};
    f4v acc[8];
#pragma unroll
    for(int i=0;i<8;++i) acc[i]=zz;

    for(int kt=0;kt<Kp;kt+=64){
        {
            int r=tid>>2, c0=(tid&3)*16;
            int gr=row0+r;
            bool vec=false;
            if constexpr (sizeof(TA)==2) vec=((K&63)==0);
            if(vec){
                const u16* src=(const u16*)(const void*)A+(size_t)gr*lda+kt+c0;
                u16x8 v0={0,0,0,0,0,0,0,0}, v1={0,0,0,0,0,0,0,0};
                if(gr<M){ v0=*(const u16x8*)src; v1=*(const u16x8*)(src+8); }
                *(u16x8*)&As[r*72+c0]=v0;
                *(u16x8*)&As[r*72+c0+8]=v1;
            } else {
                for(int c=c0;c<c0+16;++c){
                    int k=kt+c;
                    float v=(gr<M&&k<K)?ldA(A,(size_t)gr*lda+k):0.f;
                    As[r*72+c]=f2b(v);
                }
            }
        }
        {
            int n=tid>>1, k0=(tid&1)*32;
            const u16* src=Wp+(size_t)n*Kp+kt+k0;
            *(u16x8*)&Bs[n*72+k0]   =*(const u16x8*)(src);
            *(u16x8*)&Bs[n*72+k0+8] =*(const u16x8*)(src+8);
            *(u16x8*)&Bs[n*72+k0+16]=*(const u16x8*)(src+16);
            *(u16x8*)&Bs[n*72+k0+24]=*(const u16x8*)(src+24);
        }
        __syncthreads();
        const int arow=w*16+lr;
#pragma unroll
        for(int kk=0;kk<64;kk+=32){
            s8v a=*(const s8v*)&As[arow*72+kk+kg*8];
#pragma unroll
            for(int ct=0;ct<8;++ct){
                s8v bfr=*(const s8v*)&Bs[(ct*16+lr)*72+kk+kg*8];
                acc[ct]=__builtin_amdgcn_mfma_f32_16x16x32_bf16(a,bfr,acc[ct],0,0,0);
            }
        }
        __syncthreads();
    }
#pragma unroll
    for(int reg=0;reg<4;++reg){
        int gr=row0+w*16+kg*4+reg;
        if(gr>=M) continue;
        u16* crow=C+(size_t)gr*128;
#pragma unroll
        for(int ct=0;ct<8;++ct){
            int col=ct*16+lr;
            float v=acc[ct][reg];
            if(bias) v+=bias[col];
            if(ACT) v=silu_f(v);
            crow[col]=f2b(v);
        }
    }
}

// ---------------- fused node update GEMM (IN PLACE on X) -----------------------
// X = X + silu(LN(X@Wsrc + bias + U))   [row-local: safe in place]
__global__ __launch_bounds__(256)
void gemmz_k(u16* __restrict__ X, int M,
             const u16* __restrict__ Wp, const float* __restrict__ bias,
             const u16* __restrict__ U,
             const float* __restrict__ g, const float* __restrict__ b)
{
    __shared__ __align__(16) u16 As[64*72];
    __shared__ __align__(16) u16 Bs[128*72];
    const int tid=threadIdx.x, row0=blockIdx.x*64;
    const int w=tid>>6, l=tid&63, lr=l&15, kg=l>>4;
    f4v acc[8];
#pragma unroll
    for(int ct=0;ct<8;++ct){
        int col=ct*16+lr;
        float bv=bias[col];
#pragma unroll
        for(int reg=0;reg<4;++reg){
            int row=row0+w*16+kg*4+reg;
            float uv=(row<M)?b2f(U[(size_t)row*128+col]):0.f;
            acc[ct][reg]=uv+bv;
        }
    }
    for(int kt=0;kt<128;kt+=64){
        {
            int r=tid>>2, c0=(tid&3)*16;
            int gr=row0+r;
            const u16* src=X+(size_t)gr*128+kt+c0;
            u16x8 v0={0,0,0,0,0,0,0,0}, v1={0,0,0,0,0,0,0,0};
            if(gr<M){ v0=*(const u16x8*)src; v1=*(const u16x8*)(src+8); }
            *(u16x8*)&As[r*72+c0]=v0;
            *(u16x8*)&As[r*72+c0+8]=v1;
        }
        {
            int n=tid>>1, k0=(tid&1)*32;
            const u16* src=Wp+(size_t)n*128+kt+k0;
            *(u16x8*)&Bs[n*72+k0]   =*(const u16x8*)(src);
            *(u16x8*)&Bs[n*72+k0+8] =*(const u16x8*)(src+8);
            *(u16x8*)&Bs[n*72+k0+16]=*(const u16x8*)(src+16);
            *(u16x8*)&Bs[n*72+k0+24]=*(const u16x8*)(src+24);
        }
        __syncthreads();
        const int arow=w*16+lr;
#pragma unroll
        for(int kk=0;kk<64;kk+=32){
            s8v a=*(const s8v*)&As[arow*72+kk+kg*8];
#pragma unroll
            for(int ct=0;ct<8;++ct){
                s8v bfr=*(const s8v*)&Bs[(ct*16+lr)*72+kk+kg*8];
                acc[ct]=__builtin_amdgcn_mfma_f32_16x16x32_bf16(a,bfr,acc[ct],0,0,0);
            }
        }
        __syncthreads();
    }
    // epilogue: LN over row (16-lane group), silu, residual, in-place store
    float sum[4]={0.f,0.f,0.f,0.f}, sq[4]={0.f,0.f,0.f,0.f};
#pragma unroll
    for(int ct=0;ct<8;++ct)
#pragma unroll
        for(int reg=0;reg<4;++reg){
            float v=acc[ct][reg];
            sum[reg]+=v; sq[reg]+=v*v;
        }
#pragma unroll
    for(int m=1;m<16;m<<=1)
#pragma unroll
        for(int reg=0;reg<4;++reg){
            sum[reg]+=__shfl_xor(sum[reg],m,64);
            sq[reg] +=__shfl_xor(sq[reg], m,64);
        }
    float mean[4], rstd[4];
#pragma unroll
    for(int reg=0;reg<4;++reg){
        mean[reg]=sum[reg]*(1.f/128.f);
        float var=sq[reg]*(1.f/128.f)-mean[reg]*mean[reg];
        rstd[reg]=rsqrtf(var+1e-5f);
    }
#pragma unroll
    for(int ct=0;ct<8;++ct){
        int col=ct*16+lr;
        float gv=g[col], bv=b[col];
#pragma unroll
        for(int reg=0;reg<4;++reg){
            int row=row0+w*16+kg*4+reg;
            if(row<M){
                float h=gv*(acc[ct][reg]-mean[reg])*rstd[reg]+bv;
                u16* p=X+(size_t)row*128+col;
                *p=f2b(b2f(*p)+silu_f(h));
            }
        }
    }
}

// ---------------- fused CSR gather: esum + gated messages ----------------------
// FIN=0: partial — a += sig*P1[j] for j in [c0,c1) only; U[n] = raw a (bf16)
// FIN=1: es over ALL edges + a for chunk; (+prev U if HASPREV); U[n] = a/(es+eps)
template<int FIN, int HASPREV>
__global__ __launch_bounds__(256)
void gather_k(const u16* __restrict__ e, const u16* __restrict__ P1,
              u16* __restrict__ U,
              const int* __restrict__ off, const int* __restrict__ list,
              const int* __restrict__ idx, long joff,
              const int* __restrict__ iflag, int fi,
              int Nn, int c0, int c1)
{
    int st=iflag[fi];
    int wid=threadIdx.x>>6, lane=threadIdx.x&63;
    int n=blockIdx.x*4+wid; if(n>=Nn) return;
    int beg=off[n], end=off[n+1];
    float es0=0.f,es1=0.f,a0=0.f,a1=0.f;
    int k=beg;
    for(; k+1<end; k+=2){
        int eid0=list[k], eid1=list[k+1];
        int j0=idx[((size_t)joff+eid0)*st]; j0=j0<0?0:(j0>=Nn?Nn-1:j0);
        int j1=idx[((size_t)joff+eid1)*st]; j1=j1<0?0:(j1>=Nn?Nn-1:j1);
        bool in0=(j0>=c0)&&(j0<c1), in1=(j1>=c0)&&(j1<c1);
        if(FIN||in0){
            unsigned ev=*(const unsigned*)(e+(size_t)eid0*128+2*lane);
            float s0=sigm_f(b2f((u16)(ev&0xffff)));
            float s1=sigm_f(b2f((u16)(ev>>16)));
            if(FIN){ es0+=s0; es1+=s1; }
            if(in0){
                unsigned pv=*(const unsigned*)(P1+(size_t)(j0-c0)*128+2*lane);
                a0+=s0*b2f((u16)(pv&0xffff));
                a1+=s1*b2f((u16)(pv>>16));
            }
        }
        if(FIN||in1){
            unsigned ev=*(const unsigned*)(e+(size_t)eid1*128+2*lane);
            float s0=sigm_f(b2f((u16)(ev&0xffff)));
            float s1=sigm_f(b2f((u16)(ev>>16)));
            if(FIN){ es0+=s0; es1+=s1; }
            if(in1){
                unsigned pv=*(const unsigned*)(P1+(size_t)(j1-c0)*128+2*lane);
                a0+=s0*b2f((u16)(pv&0xffff));
                a1+=s1*b2f((u16)(pv>>16));
            }
        }
    }
    if(k<end){
        int eid=list[k];
        int j=idx[((size_t)joff+eid)*st]; j=j<0?0:(j>=Nn?Nn-1:j);
        bool in=(j>=c0)&&(j<c1);
        if(FIN||in){
            unsigned ev=*(const unsigned*)(e+(size_t)eid*128+2*lane);
            float s0=sigm_f(b2f((u16)(ev&0xffff)));
            float s1=sigm_f(b2f((u16)(ev>>16)));
            if(FIN){ es0+=s0; es1+=s1; }
            if(in){
                unsigned pv=*(const unsigned*)(P1+(size_t)(j-c0)*128+2*lane);
                a0+=s0*b2f((u16)(pv&0xffff));
                a1+=s1*b2f((u16)(pv>>16));
            }
        }
    }
    unsigned* up=(unsigned*)(U+(size_t)n*128+2*lane);
    if(!FIN){
        *up=((unsigned)f2b(a0))|((unsigned)f2b(a1)<<16);
    } else {
        if(HASPREV){
            unsigned pv=*up;
            a0+=b2f((u16)(pv&0xffff));
            a1+=b2f((u16)(pv>>16));
        }
        float r0=1.f/(es0+1e-5f), r1=1.f/(es1+1e-5f);
        *up=((unsigned)f2b(a0*r0))|((unsigned)f2b(a1*r1)<<16);
    }
}

// ---------------- fused edge update (MFMA), in place on e ----------------------
__global__ __launch_bounds__(256)
void edgez_k(u16* __restrict__ e, const u16* __restrict__ x,
             const int* __restrict__ idx, long joff,
             const int* __restrict__ iflag, int fi,
             const u16* __restrict__ Wep, const float* __restrict__ be,
             const float* __restrict__ g, const float* __restrict__ b,
             int Ne, int Nn)
{
    __shared__ __align__(16) u16 As[64*72];
    __shared__ __align__(16) u16 Bs[128*72];
    __shared__ int rid[128];
    const int tid=threadIdx.x, row0=blockIdx.x*64;
    const int w=tid>>6, l=tid&63, lr=l&15, kg=l>>4;
    int st=iflag[fi];
    if(tid<128){
        int r=tid&63, eid=row0+r; if(eid>=Ne) eid=Ne-1;
        long elem=(tid<64)?(long)eid:(joff+eid);
        int v=idx[(size_t)elem*st]; v=v<0?0:(v>=Nn?Nn-1:v);
        rid[tid]=v;
    }
    __syncthreads();
    f4v zz={0.f,0.f,0.f,0.f};
    f4v acc[8];
#pragma unroll
    for(int i=0;i<8;++i) acc[i]=zz;

    for(int s=0;s<6;++s){
        const int sec=s>>1, half=s&1;
        {
            int r=tid>>2, c0=(tid&3)*16;
            const u16* src;
            if(sec==0)      src=x+(size_t)rid[r]*128;
            else if(sec==1) src=x+(size_t)rid[64+r]*128;
            else { int eid=row0+r; if(eid>=Ne) eid=Ne-1; src=e+(size_t)eid*128; }
            src+=half*64+c0;
            *(u16x8*)&As[r*72+c0]  =*(const u16x8*)src;
            *(u16x8*)&As[r*72+c0+8]=*(const u16x8*)(src+8);
        }
        {
            int n=tid>>1, k0=(tid&1)*32;
            const u16* src=Wep+(size_t)n*384+s*64+k0;
            *(u16x8*)&Bs[n*72+k0]   =*(const u16x8*)(src);
            *(u16x8*)&Bs[n*72+k0+8] =*(const u16x8*)(src+8);
            *(u16x8*)&Bs[n*72+k0+16]=*(const u16x8*)(src+16);
            *(u16x8*)&Bs[n*72+k0+24]=*(const u16x8*)(src+24);
        }
        __syncthreads();
        const int arow=w*16+lr;
#pragma unroll
        for(int kk=0;kk<64;kk+=32){
            s8v a=*(const s8v*)&As[arow*72+kk+kg*8];
#pragma unroll
            for(int ct=0;ct<8;++ct){
                s8v bfr=*(const s8v*)&Bs[(ct*16+lr)*72+kk+kg*8];
                acc[ct]=__builtin_amdgcn_mfma_f32_16x16x32_bf16(a,bfr,acc[ct],0,0,0);
            }
        }
        __syncthreads();
    }
    float sum[4]={0.f,0.f,0.f,0.f}, sq[4]={0.f,0.f,0.f,0.f};
#pragma unroll
    for(int ct=0;ct<8;++ct){
        float bev=be[ct*16+lr];
#pragma unroll
        for(int reg=0;reg<4;++reg){
            float v=acc[ct][reg]+bev;
            acc[ct][reg]=v;
            sum[reg]+=v; sq[reg]+=v*v;
        }
    }
#pragma unroll
    for(int m=1;m<16;m<<=1){
#pragma unroll
        for(int reg=0;reg<4;++reg){
            sum[reg]+=__shfl_xor(sum[reg],m,64);
            sq[reg] +=__shfl_xor(sq[reg], m,64);
        }
    }
    float mean[4], rstd[4];
#pragma unroll
    for(int reg=0;reg<4;++reg){
        mean[reg]=sum[reg]*(1.f/128.f);
        float var=sq[reg]*(1.f/128.f)-mean[reg]*mean[reg];
        rstd[reg]=rsqrtf(var+1e-5f);
    }
#pragma unroll
    for(int ct=0;ct<8;++ct){
        int col=ct*16+lr;
        float gv=g[col], bv=b[col];
#pragma unroll
        for(int reg=0;reg<4;++reg){
            int eid=row0+w*16+kg*4+reg;
            if(eid<Ne){
                float h=gv*(acc[ct][reg]-mean[reg])*rstd[reg]+bv;
                u16* p=e+(size_t)eid*128+col;
                *p=f2b(b2f(*p)+silu_f(h));
            }
        }
    }
}

// ---------------- BatchNorm / pool / head --------------------------------------
__global__ __launch_bounds__(256)
void bn_stats_k(const u16* __restrict__ h, float* __restrict__ st, int N){
    int t=blockIdx.x*256+threadIdx.x;
    int d=t&127, r0=t>>7, rstride=(gridDim.x*256)>>7;
    float s=0.f,q=0.f;
    for(int r=r0;r<N;r+=rstride){ float v=b2f(h[(size_t)r*128+d]); s+=v; q+=v*v; }
    atomicAdd(&st[d],s); atomicAdd(&st[128+d],q);
}
__global__ __launch_bounds__(256)
void bn_apply_k(u16* __restrict__ h, const float* __restrict__ st,
                const float* __restrict__ g, const float* __restrict__ b, int N){
    int t=blockIdx.x*256+threadIdx.x;
    if(t>=N*128) return;
    int d=t&127;
    float inv=1.f/(float)N;
    float m=st[d]*inv, var=st[128+d]*inv-m*m;
    float v=g[d]*(b2f(h[t])-m)*rsqrtf(var+1e-5f)+b[d];
    h[t]=f2b(silu_f(v));
}
__global__ __launch_bounds__(256)
void pool_k(const u16* __restrict__ o, const int* __restrict__ batch,
            const int* __restrict__ iflag,
            float* __restrict__ pooled, float* __restrict__ cnt, int N, int NG){
    int st=iflag[2];
    int wid=threadIdx.x>>6, lane=threadIdx.x&63;
    int n=blockIdx.x*4+wid; if(n>=N) return;
    int gi=batch[(size_t)n*st]; gi=gi<0?0:(gi>=NG?NG-1:gi);
    atomicAdd(&pooled[(size_t)gi*128+lane],    b2f(o[(size_t)n*128+lane]));
    atomicAdd(&pooled[(size_t)gi*128+64+lane], b2f(o[(size_t)n*128+64+lane]));
    if(lane==0) atomicAdd(&cnt[gi],1.f);
}
__global__ void final_k(const float* __restrict__ pooled, const float* __restrict__ cnt,
                        const float* __restrict__ oW, const float* __restrict__ ob,
                        float* __restrict__ out){
    int gi=blockIdx.x, lane=threadIdx.x;
    float v=pooled[(size_t)gi*128+lane]*oW[lane]
           +pooled[(size_t)gi*128+64+lane]*oW[64+lane];
    for(int m=32;m;m>>=1) v+=__shfl_xor(v,m,64);
    if(lane==0) out[gi]=v/fmaxf(cnt[gi],1.f)+ob[0];
}

// -------------------------------------------------------------------------------
template<typename TA>
static inline void gemm(hipStream_t s, const TA* A, int lda, int M, int K, int Kp,
                        const u16* Wp, const float* bias, u16* C, int act){
    dim3 grid((M+63)/64);
    if(act) gemm_k<TA,1><<<grid,256,0,s>>>(A,lda,M,K,Kp,Wp,bias,C);
    else    gemm_k<TA,0><<<grid,256,0,s>>>(A,lda,M,K,Kp,Wp,bias,C);
}

static inline void build_csr(hipStream_t s, const int* idx, int fi, const int* iflag,
                             int Ne, int Nn, int* off, int* cur, int* list, int* tot){
    int nb=(Nn+SCH-1)/SCH;
    zero_i_k<<<256,256,0,s>>>(cur,Nn);
    hist_k<<<(Ne+255)/256,256,0,s>>>(idx,iflag,fi,cur,Ne,Nn);
    scan1_k<<<nb,256,0,s>>>(cur,tot,Nn);
    scan2_k<<<1,1,0,s>>>(tot,nb);
    scan3_k<<<nb,256,0,s>>>(cur,tot,off,Nn,Ne);
    zero_i_k<<<256,256,0,s>>>(cur,Nn);
    fill_k<<<(Ne+255)/256,256,0,s>>>(idx,iflag,fi,off,cur,list,Ne,Nn);
}

static inline void pack_w(hipStream_t s, const float* W, u16* Wp, int K, int Kp){
    pack_w_k<<<(128*Kp+255)/256,256,0,s>>>(W,Wp,K,Kp);
}

extern "C" void kernel_launch(void* const* d_in, const int* in_sizes, int n_in,
                              void* d_out, int out_size, void* d_ws, size_t ws_size,
                              hipStream_t stream)
{
    const float* x_in =(const float*)d_in[0];
    const float* ea   =(const float*)d_in[1];
    const float* eal  =(const float*)d_in[2];
    const int*   ei   =(const int*)d_in[3];
    const int*   eil  =(const int*)d_in[4];
    const int*   batch=(const int*)d_in[5];
    const float* pre1W=(const float*)d_in[6];  const float* pre1b=(const float*)d_in[7];
    const float* pre2W=(const float*)d_in[8];  const float* pre2b=(const float*)d_in[9];
    const float* pre3W=(const float*)d_in[10]; const float* pre3b=(const float*)d_in[11];
    const float* lWsrc=(const float*)d_in[12]; const float* lbsrc=(const float*)d_in[13];
    const float* lWdst=(const float*)d_in[14]; const float* lbdst=(const float*)d_in[15];
    const float* lWe  =(const float*)d_in[16]; const float* lbe  =(const float*)d_in[17];
    const float* lnxg =(const float*)d_in[18]; const float* lnxb =(const float*)d_in[19];
    const float* lneg =(const float*)d_in[20]; const float* lneb =(const float*)d_in[21];
    const float* aWsrc=(const float*)d_in[22]; const float* absrc=(const float*)d_in[23];
    const float* aWdst=(const float*)d_in[24]; const float* abdst=(const float*)d_in[25];
    const float* aWe  =(const float*)d_in[26]; const float* abe  =(const float*)d_in[27];
    const float* anxg =(const float*)d_in[28]; const float* anxb =(const float*)d_in[29];
    const float* aneg =(const float*)d_in[30]; const float* aneb =(const float*)d_in[31];
    const float* bng  =(const float*)d_in[32]; const float* bnb  =(const float*)d_in[33];
    const float* postW=(const float*)d_in[34]; const float* postb=(const float*)d_in[35];
    const float* outW =(const float*)d_in[36]; const float* outb =(const float*)d_in[37];
    (void)n_in;

    const int N =in_sizes[5];
    const int E =in_sizes[3]/2;
    const int EL=in_sizes[4]/2;
    const int NG=out_size;
    const int CH=(E+1)/2;

    char* base=(char*)d_ws;
    size_t off=0;
    auto alloc=[&](size_t bytes)->char*{
        char* p=base+off; off=(off+bytes+255)&~(size_t)255; return p;
    };
    u16* hN   =(u16*)alloc((size_t)N*128*2);
    u16* hE   =(u16*)alloc((size_t)E*128*2);
    u16* hL   =(u16*)alloc((size_t)EL*128*2);
    u16* U    =(u16*)alloc((size_t)E*128*2);
    u16* P1   =(u16*)alloc((size_t)CH*128*2);     // also post-FC output
    int* off_l=(int*)alloc((size_t)(E+1)*4);
    int* cur_l=(int*)alloc((size_t)E*4);
    int* list_l=(int*)alloc((size_t)EL*4);
    int* off_a=(int*)alloc((size_t)(N+1)*4);
    int* cur_a=(int*)alloc((size_t)N*4);
    int* list_a=(int*)alloc((size_t)E*4);
    int* tot  =(int*)alloc(4096);
    int* iflag=(int*)alloc(64);
    float* stats =(float*)alloc(256*4);
    float* pooled=(float*)alloc((size_t)NG*128*4);
    float* cnt   =(float*)alloc((size_t)NG*4);
    u16* pre1p=(u16*)alloc(128*128*2);
    u16* pre2p=(u16*)alloc(128*64*2);
    u16* pre3p=(u16*)alloc(128*64*2);
    u16* postp=(u16*)alloc(128*128*2);
    u16 *lsrcp[4],*ldstp[4],*lWep[4],*asrcp[4],*adstp[4],*aWep[4];
    for(int i=0;i<4;i++){
        lsrcp[i]=(u16*)alloc(128*128*2);
        ldstp[i]=(u16*)alloc(128*128*2);
        lWep[i] =(u16*)alloc(128*384*2);
        asrcp[i]=(u16*)alloc(128*128*2);
        adstp[i]=(u16*)alloc(128*128*2);
        aWep[i] =(u16*)alloc(128*384*2);
    }
    if(off>ws_size){
        diag_k<<<(NG+255)/256,256,0,stream>>>((float*)d_out,NG,(float)(ws_size>>20)+0.25f);
        return;
    }

    probe_k<<<1,64,0,stream>>>(ei,eil,batch,N,iflag);
    build_csr(stream,eil,1,iflag,EL,E,off_l,cur_l,list_l,tot);
    build_csr(stream,ei, 0,iflag,E, N,off_a,cur_a,list_a,tot);

    pack_w(stream,pre1W,pre1p,92,128);
    pack_w(stream,pre2W,pre2p,50,64);
    pack_w(stream,pre3W,pre3p,40,64);
    pack_w(stream,postW,postp,128,128);
    for(int i=0;i<4;i++){
        pack_w(stream,lWsrc+(size_t)i*128*128,lsrcp[i],128,128);
        pack_w(stream,lWdst+(size_t)i*128*128,ldstp[i],128,128);
        pack_w(stream,lWe  +(size_t)i*384*128,lWep[i],384,384);
        pack_w(stream,aWsrc+(size_t)i*128*128,asrcp[i],128,128);
        pack_w(stream,aWdst+(size_t)i*128*128,adstp[i],128,128);
        pack_w(stream,aWe  +(size_t)i*384*128,aWep[i],384,384);
    }

    gemm(stream,x_in,92,N, 92,128,pre1p,pre1b,hN,1);
    gemm(stream,ea,  50,E, 50, 64,pre2p,pre2b,hE,1);
    gemm(stream,eal, 40,EL,40, 64,pre3p,pre3b,hL,1);

    for(int l=0;l<NCONV_DEF;++l){
        {   // ===== line conv: nodes=hE (E), edges=hL (EL) =====
            // chunk 0 messages (raw partial into U)
            gemm(stream,hE,128,CH,128,128,ldstp[l],lbdst+l*128,P1,0);
            gather_k<0,0><<<(E+3)/4,256,0,stream>>>(hL,P1,U,off_l,list_l,
                                                    eil,EL,iflag,1,E,0,CH);
            // chunk 1 messages + esum + finalize gated agg
            gemm(stream,hE+(size_t)CH*128,128,E-CH,128,128,ldstp[l],lbdst+l*128,P1,0);
            gather_k<1,1><<<(E+3)/4,256,0,stream>>>(hL,P1,U,off_l,list_l,
                                                    eil,EL,iflag,1,E,CH,E);
            // edge update (consumes OLD hE, in place on hL)
            edgez_k<<<(EL+63)/64,256,0,stream>>>(hL,hE,eil,EL,iflag,1,
                                                 lWep[l],lbe+l*128,lneg+l*128,lneb+l*128,EL,E);
            // node update (in place on hE): hE += silu(LN(hE@Wsrc+b+U))
            gemmz_k<<<(E+63)/64,256,0,stream>>>(hE,E,lsrcp[l],lbsrc+l*128,U,
                                                lnxg+l*128,lnxb+l*128);
        }
        {   // ===== atom conv: nodes=hN (N), edges=hE (E) =====
            gemm(stream,hN,128,N,128,128,adstp[l],abdst+l*128,P1,0);
            gather_k<1,0><<<(N+3)/4,256,0,stream>>>(hE,P1,U,off_a,list_a,
                                                    ei,E,iflag,0,N,0,N);
            edgez_k<<<(E+63)/64,256,0,stream>>>(hE,hN,ei,E,iflag,0,
                                                aWep[l],abe+l*128,aneg+l*128,aneb+l*128,E,N);
            gemmz_k<<<(N+63)/64,256,0,stream>>>(hN,N,asrcp[l],absrc+l*128,U,
                                                anxg+l*128,anxb+l*128);
        }
    }

    zero_f_k<<<64,256,0,stream>>>(stats,256);
    zero_f_k<<<64,256,0,stream>>>(pooled,(long)NG*128);
    zero_f_k<<<1,256,0,stream>>>(cnt,NG);
    bn_stats_k<<<256,256,0,stream>>>(hN,stats,N);
    bn_apply_k<<<(N*128+255)/256,256,0,stream>>>(hN,stats,bng,bnb,N);

    gemm(stream,hN,128,N,128,128,postp,postb,P1,1);

    pool_k<<<(N+3)/4,256,0,stream>>>(P1,batch,iflag,pooled,cnt,N,NG);
    final_k<<<NG,64,0,stream>>>(pooled,cnt,outW,outb,(float*)d_out);
}

// Round 6
// 3639.606 us; speedup vs baseline: 3.1273x; 1.2181x over previous
//
#include <hip/hip_runtime.h>

#define NCONV_DEF 4
#define SCH 1024

typedef unsigned short u16;
typedef __attribute__((ext_vector_type(8))) short s8v;      // MFMA bf16 A/B frag
typedef __attribute__((ext_vector_type(4))) float f4v;      // MFMA C/D frag
typedef __attribute__((ext_vector_type(8))) unsigned short u16x8;

__device__ __forceinline__ float sigm_f(float x){ return 1.f/(1.f+__expf(-x)); }
__device__ __forceinline__ float silu_f(float x){ return x/(1.f+__expf(-x)); }
__device__ __forceinline__ float b2f(u16 h){ union{unsigned u; float f;} v; v.u=(unsigned)h<<16; return v.f; }
__device__ __forceinline__ u16 f2b(float f){ union{float f; unsigned u;} v; v.f=f; unsigned r=v.u+0x7fffu+((v.u>>16)&1u); return (u16)(r>>16); }
__device__ __forceinline__ float ldAv(const float* p, size_t i){ return p[i]; }
__device__ __forceinline__ float ldAv(const u16* p, size_t i){ return b2f(p[i]); }

#define EPS_ 136   // epilogue LDS row stride in u16 (272B, 16B-aligned)

__global__ __launch_bounds__(256) void zero_f_k(float* p, long n){
    long i=(long)blockIdx.x*256+threadIdx.x, st=(long)gridDim.x*256;
    for(;i<n;i+=st) p[i]=0.f;
}
__global__ __launch_bounds__(256) void zero_i_k(int* p, long n){
    long i=(long)blockIdx.x*256+threadIdx.x, st=(long)gridDim.x*256;
    for(;i<n;i+=st) p[i]=0;
}
__global__ void diag_k(float* out, int n, float v){
    int i=blockIdx.x*256+threadIdx.x; if(i<n) out[i]=v;
}
__global__ void probe_k(const int* ei, const int* eil, const int* batch, int nb, int* flag){
    if(threadIdx.x||blockIdx.x) return;
    int a=2,b=2,c=2;
    for(int k=0;k<64;k++){ if(ei[2*k+1]!=0) a=1; if(eil[2*k+1]!=0) b=1; }
    int base=nb-128;
    for(int k=0;k<64;k++){ if(batch[base+2*k+1]!=0) c=1; }
    flag[0]=a; flag[1]=b; flag[2]=c;
}

// ---------------- CSR build ----------------------------------------------------
__global__ __launch_bounds__(256)
void hist_k(const int* __restrict__ idx, const int* __restrict__ iflag, int fi,
            int* __restrict__ cnt, int Ne, int Nn){
    int e=blockIdx.x*256+threadIdx.x; if(e>=Ne) return;
    int st=iflag[fi];
    int i=idx[(size_t)e*st]; i=i<0?0:(i>=Nn?Nn-1:i);
    atomicAdd(&cnt[i],1);
}
__global__ __launch_bounds__(256)
void scan1_k(const int* cnt, int* tot, int n){
    __shared__ int sh[256];
    int base=blockIdx.x*SCH, s=0;
    for(int t=threadIdx.x;t<SCH;t+=256){ int i=base+t; s+=(i<n)?cnt[i]:0; }
    sh[threadIdx.x]=s; __syncthreads();
    for(int o=128;o;o>>=1){ if(threadIdx.x<o) sh[threadIdx.x]+=sh[threadIdx.x+o]; __syncthreads(); }
    if(threadIdx.x==0) tot[blockIdx.x]=sh[0];
}
__global__ void scan2_k(int* tot, int nb){
    if(threadIdx.x==0&&blockIdx.x==0){ int acc=0; for(int i=0;i<nb;i++){int v=tot[i]; tot[i]=acc; acc+=v;} }
}
__global__ __launch_bounds__(256)
void scan3_k(const int* cnt, const int* tot, int* off, int n, int total){
    __shared__ int sh[256];
    int b=blockIdx.x, t4=b*SCH+threadIdx.x*4;
    int v0=(t4+0<n)?cnt[t4+0]:0, v1=(t4+1<n)?cnt[t4+1]:0;
    int v2=(t4+2<n)?cnt[t4+2]:0, v3=(t4+3<n)?cnt[t4+3]:0;
    int ls=v0+v1+v2+v3;
    sh[threadIdx.x]=ls; __syncthreads();
    for(int o=1;o<256;o<<=1){
        int val=(threadIdx.x>=o)?sh[threadIdx.x-o]:0; __syncthreads();
        sh[threadIdx.x]+=val; __syncthreads();
    }
    int excl=sh[threadIdx.x]-ls+tot[b];
    if(t4+0<n) off[t4+0]=excl;
    if(t4+1<n) off[t4+1]=excl+v0;
    if(t4+2<n) off[t4+2]=excl+v0+v1;
    if(t4+3<n) off[t4+3]=excl+v0+v1+v2;
    if(b==(int)gridDim.x-1&&threadIdx.x==255) off[n]=total;
}
__global__ __launch_bounds__(256)
void fill_k(const int* __restrict__ idx, const int* __restrict__ iflag, int fi,
            const int* __restrict__ off, int* __restrict__ cur, int* __restrict__ list,
            int Ne, int Nn){
    int e=blockIdx.x*256+threadIdx.x; if(e>=Ne) return;
    int st=iflag[fi];
    int i=idx[(size_t)e*st]; i=i<0?0:(i>=Nn?Nn-1:i);
    int pos=off[i]+atomicAdd(&cur[i],1);
    list[pos]=e;
}

// ---------------- weight pack: W[K][128] f32 -> Wp[128][Kp] bf16 ---------------
__global__ __launch_bounds__(256)
void pack_w_k(const float* __restrict__ W, u16* __restrict__ Wp, int K, int Kp){
    int i=blockIdx.x*256+threadIdx.x;
    if(i>=128*Kp) return;
    int n=i/Kp, k=i-n*Kp;
    Wp[i] = (k<K) ? f2b(W[(size_t)k*128+n]) : (u16)0;
}

// ---------------- MFMA GEMM: C[M,128] = A[M,K] @ W[K,128] (+bias)(+silu) -------
template<typename TA, int ACT>
__global__ __launch_bounds__(256)
void gemm_k(const TA* __restrict__ A, int lda, int M, int K, int Kp,
            const u16* __restrict__ Wp, const float* __restrict__ bias,
            u16* __restrict__ C)
{
    __shared__ __align__(16) u16 As[64*72];
    __shared__ __align__(16) u16 Bs[128*72];
    const int tid=threadIdx.x, row0=blockIdx.x*64;
    const int w=tid>>6, l=tid&63, lr=l&15, kg=l>>4;
    f4v zz={0.f,0.f,0.f,0.f};
    f4v acc[8];
#pragma unroll
    for(int i=0;i<8;++i) acc[i]=zz;

    for(int kt=0;kt<Kp;kt+=64){
        {
            int r=tid>>2, c0=(tid&3)*16;
            int gr=row0+r;
            bool vec=false;
            if constexpr (sizeof(TA)==2) vec=((K&63)==0);
            if(vec){
                const u16* src=(const u16*)(const void*)A+(size_t)gr*lda+kt+c0;
                u16x8 v0={0,0,0,0,0,0,0,0}, v1={0,0,0,0,0,0,0,0};
                if(gr<M){ v0=*(const u16x8*)src; v1=*(const u16x8*)(src+8); }
                *(u16x8*)&As[r*72+c0]=v0;
                *(u16x8*)&As[r*72+c0+8]=v1;
            } else {
                for(int c=c0;c<c0+16;++c){
                    int k=kt+c;
                    float v=(gr<M&&k<K)?ldAv(A,(size_t)gr*lda+k):0.f;
                    As[r*72+c]=f2b(v);
                }
            }
        }
        {
            int n=tid>>1, k0=(tid&1)*32;
            const u16* src=Wp+(size_t)n*Kp+kt+k0;
            *(u16x8*)&Bs[n*72+k0]   =*(const u16x8*)(src);
            *(u16x8*)&Bs[n*72+k0+8] =*(const u16x8*)(src+8);
            *(u16x8*)&Bs[n*72+k0+16]=*(const u16x8*)(src+16);
            *(u16x8*)&Bs[n*72+k0+24]=*(const u16x8*)(src+24);
        }
        __syncthreads();
        const int arow=w*16+lr;
#pragma unroll
        for(int kk=0;kk<64;kk+=32){
            s8v a=*(const s8v*)&As[arow*72+kk+kg*8];
#pragma unroll
            for(int ct=0;ct<8;++ct){
                s8v bfr=*(const s8v*)&Bs[(ct*16+lr)*72+kk+kg*8];
                acc[ct]=__builtin_amdgcn_mfma_f32_16x16x32_bf16(a,bfr,acc[ct],0,0,0);
            }
        }
        __syncthreads();
    }
    // ---- vectorized epilogue via LDS round-trip ----
    u16* ep=Bs;
#pragma unroll
    for(int ct=0;ct<8;++ct){
        int col=ct*16+lr;
        float bv=bias?bias[col]:0.f;
#pragma unroll
        for(int reg=0;reg<4;++reg){
            float v=acc[ct][reg]+bv;
            if(ACT) v=silu_f(v);
            ep[(w*16+kg*4+reg)*EPS_+col]=f2b(v);
        }
    }
    __syncthreads();
    {
        int ar=tid>>2, gr=row0+ar;
        if(gr<M){
            u16* crow=C+(size_t)gr*128+(tid&3)*32;
            const u16* hrow=&ep[ar*EPS_+(tid&3)*32];
#pragma unroll
            for(int c4=0;c4<4;++c4)
                *(u16x8*)(crow+c4*8)=*(const u16x8*)(hrow+c4*8);
        }
    }
}

// ---------------- fused node update GEMM (IN PLACE on X) -----------------------
// X = X + silu(LN(X@Wsrc + bias + U))   [row-local: safe in place]
__global__ __launch_bounds__(256)
void gemmz_k(u16* __restrict__ X, int M,
             const u16* __restrict__ Wp, const float* __restrict__ bias,
             const u16* __restrict__ U,
             const float* __restrict__ g, const float* __restrict__ b)
{
    __shared__ __align__(16) u16 As[64*72];
    __shared__ __align__(16) u16 Bs[128*72];
    const int tid=threadIdx.x, row0=blockIdx.x*64;
    const int w=tid>>6, l=tid&63, lr=l&15, kg=l>>4;
    u16* ep=Bs;
    // stage U coalesced -> LDS
    {
        int ar=tid>>2, gr=row0+ar;
        u16x8 z8={0,0,0,0,0,0,0,0};
        u16x8 u0=z8,u1=z8,u2=z8,u3=z8;
        if(gr<M){
            const u16* ur=U+(size_t)gr*128+(tid&3)*32;
            u0=*(const u16x8*)(ur); u1=*(const u16x8*)(ur+8);
            u2=*(const u16x8*)(ur+16); u3=*(const u16x8*)(ur+24);
        }
        u16* d=&ep[(tid>>2)*EPS_+(tid&3)*32];
        *(u16x8*)(d)=u0; *(u16x8*)(d+8)=u1; *(u16x8*)(d+16)=u2; *(u16x8*)(d+24)=u3;
    }
    __syncthreads();
    f4v acc[8];
#pragma unroll
    for(int ct=0;ct<8;++ct){
        int col=ct*16+lr;
        float bv=bias[col];
#pragma unroll
        for(int reg=0;reg<4;++reg)
            acc[ct][reg]=b2f(ep[(w*16+kg*4+reg)*EPS_+col])+bv;
    }
    __syncthreads();   // before K-loop overwrites Bs

    for(int kt=0;kt<128;kt+=64){
        {
            int r=tid>>2, c0=(tid&3)*16;
            int gr=row0+r;
            const u16* src=X+(size_t)gr*128+kt+c0;
            u16x8 v0={0,0,0,0,0,0,0,0}, v1={0,0,0,0,0,0,0,0};
            if(gr<M){ v0=*(const u16x8*)src; v1=*(const u16x8*)(src+8); }
            *(u16x8*)&As[r*72+c0]=v0;
            *(u16x8*)&As[r*72+c0+8]=v1;
        }
        {
            int n=tid>>1, k0=(tid&1)*32;
            const u16* src=Wp+(size_t)n*128+kt+k0;
            *(u16x8*)&Bs[n*72+k0]   =*(const u16x8*)(src);
            *(u16x8*)&Bs[n*72+k0+8] =*(const u16x8*)(src+8);
            *(u16x8*)&Bs[n*72+k0+16]=*(const u16x8*)(src+16);
            *(u16x8*)&Bs[n*72+k0+24]=*(const u16x8*)(src+24);
        }
        __syncthreads();
        const int arow=w*16+lr;
#pragma unroll
        for(int kk=0;kk<64;kk+=32){
            s8v a=*(const s8v*)&As[arow*72+kk+kg*8];
#pragma unroll
            for(int ct=0;ct<8;++ct){
                s8v bfr=*(const s8v*)&Bs[(ct*16+lr)*72+kk+kg*8];
                acc[ct]=__builtin_amdgcn_mfma_f32_16x16x32_bf16(a,bfr,acc[ct],0,0,0);
            }
        }
        __syncthreads();
    }
    // LN over row (16-lane group)
    float sum[4]={0.f,0.f,0.f,0.f}, sq[4]={0.f,0.f,0.f,0.f};
#pragma unroll
    for(int ct=0;ct<8;++ct)
#pragma unroll
        for(int reg=0;reg<4;++reg){
            float v=acc[ct][reg];
            sum[reg]+=v; sq[reg]+=v*v;
        }
#pragma unroll
    for(int m=1;m<16;m<<=1)
#pragma unroll
        for(int reg=0;reg<4;++reg){
            sum[reg]+=__shfl_xor(sum[reg],m,64);
            sq[reg] +=__shfl_xor(sq[reg], m,64);
        }
    float mean[4], rstd[4];
#pragma unroll
    for(int reg=0;reg<4;++reg){
        mean[reg]=sum[reg]*(1.f/128.f);
        float var=sq[reg]*(1.f/128.f)-mean[reg]*mean[reg];
        rstd[reg]=rsqrtf(var+1e-5f);
    }
    // silu(h) -> LDS -> coalesced residual RMW
#pragma unroll
    for(int ct=0;ct<8;++ct){
        int col=ct*16+lr;
        float gv=g[col], bv=b[col];
#pragma unroll
        for(int reg=0;reg<4;++reg){
            float h=gv*(acc[ct][reg]-mean[reg])*rstd[reg]+bv;
            ep[(w*16+kg*4+reg)*EPS_+col]=f2b(silu_f(h));
        }
    }
    __syncthreads();
    {
        int ar=tid>>2, gr=row0+ar;
        if(gr<M){
            u16* xrow=X+(size_t)gr*128+(tid&3)*32;
            const u16* hrow=&ep[ar*EPS_+(tid&3)*32];
#pragma unroll
            for(int c4=0;c4<4;++c4){
                u16x8 xv=*(const u16x8*)(xrow+c4*8);
                u16x8 hv=*(const u16x8*)(hrow+c4*8);
                u16x8 ov;
#pragma unroll
                for(int j=0;j<8;++j) ov[j]=f2b(b2f(xv[j])+b2f(hv[j]));
                *(u16x8*)(xrow+c4*8)=ov;
            }
        }
    }
}

// ---------------- fused CSR gather: esum + gated messages ----------------------
template<int FIN, int HASPREV>
__global__ __launch_bounds__(256)
void gather_k(const u16* __restrict__ e, const u16* __restrict__ P1,
              u16* __restrict__ U,
              const int* __restrict__ off, const int* __restrict__ list,
              const int* __restrict__ idx, long joff,
              const int* __restrict__ iflag, int fi,
              int Nn, int c0, int c1)
{
    int st=iflag[fi];
    int wid=threadIdx.x>>6, lane=threadIdx.x&63;
    int n=blockIdx.x*4+wid; if(n>=Nn) return;
    int beg=off[n], end=off[n+1];
    float es0=0.f,es1=0.f,a0=0.f,a1=0.f;
    int k=beg;
    for(; k+1<end; k+=2){
        int eid0=list[k], eid1=list[k+1];
        int j0=idx[((size_t)joff+eid0)*st]; j0=j0<0?0:(j0>=Nn?Nn-1:j0);
        int j1=idx[((size_t)joff+eid1)*st]; j1=j1<0?0:(j1>=Nn?Nn-1:j1);
        bool in0=(j0>=c0)&&(j0<c1), in1=(j1>=c0)&&(j1<c1);
        if(FIN||in0){
            unsigned ev=*(const unsigned*)(e+(size_t)eid0*128+2*lane);
            float s0=sigm_f(b2f((u16)(ev&0xffff)));
            float s1=sigm_f(b2f((u16)(ev>>16)));
            if(FIN){ es0+=s0; es1+=s1; }
            if(in0){
                unsigned pv=*(const unsigned*)(P1+(size_t)(j0-c0)*128+2*lane);
                a0+=s0*b2f((u16)(pv&0xffff));
                a1+=s1*b2f((u16)(pv>>16));
            }
        }
        if(FIN||in1){
            unsigned ev=*(const unsigned*)(e+(size_t)eid1*128+2*lane);
            float s0=sigm_f(b2f((u16)(ev&0xffff)));
            float s1=sigm_f(b2f((u16)(ev>>16)));
            if(FIN){ es0+=s0; es1+=s1; }
            if(in1){
                unsigned pv=*(const unsigned*)(P1+(size_t)(j1-c0)*128+2*lane);
                a0+=s0*b2f((u16)(pv&0xffff));
                a1+=s1*b2f((u16)(pv>>16));
            }
        }
    }
    if(k<end){
        int eid=list[k];
        int j=idx[((size_t)joff+eid)*st]; j=j<0?0:(j>=Nn?Nn-1:j);
        bool in=(j>=c0)&&(j<c1);
        if(FIN||in){
            unsigned ev=*(const unsigned*)(e+(size_t)eid*128+2*lane);
            float s0=sigm_f(b2f((u16)(ev&0xffff)));
            float s1=sigm_f(b2f((u16)(ev>>16)));
            if(FIN){ es0+=s0; es1+=s1; }
            if(in){
                unsigned pv=*(const unsigned*)(P1+(size_t)(j-c0)*128+2*lane);
                a0+=s0*b2f((u16)(pv&0xffff));
                a1+=s1*b2f((u16)(pv>>16));
            }
        }
    }
    unsigned* up=(unsigned*)(U+(size_t)n*128+2*lane);
    if(!FIN){
        *up=((unsigned)f2b(a0))|((unsigned)f2b(a1)<<16);
    } else {
        if(HASPREV){
            unsigned pv=*up;
            a0+=b2f((u16)(pv&0xffff));
            a1+=b2f((u16)(pv>>16));
        }
        float r0=1.f/(es0+1e-5f), r1=1.f/(es1+1e-5f);
        *up=((unsigned)f2b(a0*r0))|((unsigned)f2b(a1*r1)<<16);
    }
}

// ---------------- fused edge update (MFMA, pipelined), in place on e -----------
__global__ __launch_bounds__(256)
void edgez_k(u16* __restrict__ e, const u16* __restrict__ x,
             const int* __restrict__ idx, long joff,
             const int* __restrict__ iflag, int fi,
             const u16* __restrict__ Wep, const float* __restrict__ be,
             const float* __restrict__ g, const float* __restrict__ b,
             int Ne, int Nn)
{
    __shared__ __align__(16) u16 As[64*72];
    __shared__ __align__(16) u16 Bs[128*72];
    __shared__ int rid[128];
    const int tid=threadIdx.x, row0=blockIdx.x*64;
    const int w=tid>>6, l=tid&63, lr=l&15, kg=l>>4;
    int st=iflag[fi];
    if(tid<128){
        int r=tid&63, eid=row0+r; if(eid>=Ne) eid=Ne-1;
        long elem=(tid<64)?(long)eid:(joff+eid);
        int v=idx[(size_t)elem*st]; v=v<0?0:(v>=Nn?Nn-1:v);
        rid[tid]=v;
    }
    __syncthreads();
    const int ar=tid>>2, ac=(tid&3)*16;
    const int bn=tid>>1, bk=(tid&1)*32;
    int eidA=row0+ar; if(eidA>=Ne) eidA=Ne-1;
    const u16* aptr0=x+(size_t)rid[ar]*128;
    const u16* aptr1=x+(size_t)rid[64+ar]*128;
    const u16* aptr2=e+(size_t)eidA*128;

    f4v zz={0.f,0.f,0.f,0.f};
    f4v acc[8];
#pragma unroll
    for(int i=0;i<8;++i) acc[i]=zz;

    u16x8 a0,a1,b0,b1,b2,b3;
    {   // prefetch s=0
        const u16* src=aptr0+ac;
        a0=*(const u16x8*)src; a1=*(const u16x8*)(src+8);
        const u16* wsrc=Wep+(size_t)bn*384+bk;
        b0=*(const u16x8*)wsrc; b1=*(const u16x8*)(wsrc+8);
        b2=*(const u16x8*)(wsrc+16); b3=*(const u16x8*)(wsrc+24);
    }
    for(int s=0;s<6;++s){
        __syncthreads();                 // prev MFMA done with LDS
        *(u16x8*)&As[ar*72+ac]  =a0;
        *(u16x8*)&As[ar*72+ac+8]=a1;
        *(u16x8*)&Bs[bn*72+bk]   =b0;
        *(u16x8*)&Bs[bn*72+bk+8] =b1;
        *(u16x8*)&Bs[bn*72+bk+16]=b2;
        *(u16x8*)&Bs[bn*72+bk+24]=b3;
        if(s<5){                         // prefetch s+1 (hidden under MFMA)
            int sn=s+1, sec=sn>>1, half=sn&1;
            const u16* src=(sec==0?aptr0:(sec==1?aptr1:aptr2))+half*64+ac;
            a0=*(const u16x8*)src; a1=*(const u16x8*)(src+8);
            const u16* wsrc=Wep+(size_t)bn*384+sn*64+bk;
            b0=*(const u16x8*)wsrc; b1=*(const u16x8*)(wsrc+8);
            b2=*(const u16x8*)(wsrc+16); b3=*(const u16x8*)(wsrc+24);
        }
        __syncthreads();
        __builtin_amdgcn_s_setprio(1);
        const int arow=w*16+lr;
#pragma unroll
        for(int kk=0;kk<64;kk+=32){
            s8v a=*(const s8v*)&As[arow*72+kk+kg*8];
#pragma unroll
            for(int ct=0;ct<8;++ct){
                s8v bfr=*(const s8v*)&Bs[(ct*16+lr)*72+kk+kg*8];
                acc[ct]=__builtin_amdgcn_mfma_f32_16x16x32_bf16(a,bfr,acc[ct],0,0,0);
            }
        }
        __builtin_amdgcn_s_setprio(0);
    }
    __syncthreads();                     // MFMA(5) done before LDS reuse
    // LN stats
    float sum[4]={0.f,0.f,0.f,0.f}, sq[4]={0.f,0.f,0.f,0.f};
#pragma unroll
    for(int ct=0;ct<8;++ct){
        float bev=be[ct*16+lr];
#pragma unroll
        for(int reg=0;reg<4;++reg){
            float v=acc[ct][reg]+bev;
            acc[ct][reg]=v;
            sum[reg]+=v; sq[reg]+=v*v;
        }
    }
#pragma unroll
    for(int m=1;m<16;m<<=1){
#pragma unroll
        for(int reg=0;reg<4;++reg){
            sum[reg]+=__shfl_xor(sum[reg],m,64);
            sq[reg] +=__shfl_xor(sq[reg], m,64);
        }
    }
    float mean[4], rstd[4];
#pragma unroll
    for(int reg=0;reg<4;++reg){
        mean[reg]=sum[reg]*(1.f/128.f);
        float var=sq[reg]*(1.f/128.f)-mean[reg]*mean[reg];
        rstd[reg]=rsqrtf(var+1e-5f);
    }
    // silu(h) -> LDS -> coalesced residual RMW
    u16* ep=Bs;
#pragma unroll
    for(int ct=0;ct<8;++ct){
        int col=ct*16+lr;
        float gv=g[col], bv=b[col];
#pragma unroll
        for(int reg=0;reg<4;++reg){
            float h=gv*(acc[ct][reg]-mean[reg])*rstd[reg]+bv;
            ep[(w*16+kg*4+reg)*EPS_+col]=f2b(silu_f(h));
        }
    }
    __syncthreads();
    {
        int eid=row0+ar;
        if(eid<Ne){
            u16* erow=e+(size_t)eid*128+(tid&3)*32;
            const u16* hrow=&ep[ar*EPS_+(tid&3)*32];
#pragma unroll
            for(int c4=0;c4<4;++c4){
                u16x8 ev=*(const u16x8*)(erow+c4*8);
                u16x8 hv=*(const u16x8*)(hrow+c4*8);
                u16x8 ov;
#pragma unroll
                for(int j=0;j<8;++j) ov[j]=f2b(b2f(ev[j])+b2f(hv[j]));
                *(u16x8*)(erow+c4*8)=ov;
            }
        }
    }
}

// ---------------- BatchNorm / pool / head --------------------------------------
__global__ __launch_bounds__(256)
void bn_stats_k(const u16* __restrict__ h, float* __restrict__ st, int N){
    int t=blockIdx.x*256+threadIdx.x;
    int d=t&127, r0=t>>7, rstride=(gridDim.x*256)>>7;
    float s=0.f,q=0.f;
    for(int r=r0;r<N;r+=rstride){ float v=b2f(h[(size_t)r*128+d]); s+=v; q+=v*v; }
    atomicAdd(&st[d],s); atomicAdd(&st[128+d],q);
}
__global__ __launch_bounds__(256)
void bn_apply_k(u16* __restrict__ h, const float* __restrict__ st,
                const float* __restrict__ g, const float* __restrict__ b, int N){
    int t=blockIdx.x*256+threadIdx.x;
    if(t>=N*128) return;
    int d=t&127;
    float inv=1.f/(float)N;
    float m=st[d]*inv, var=st[128+d]*inv-m*m;
    float v=g[d]*(b2f(h[t])-m)*rsqrtf(var+1e-5f)+b[d];
    h[t]=f2b(silu_f(v));
}
__global__ __launch_bounds__(256)
void pool_k(const u16* __restrict__ o, const int* __restrict__ batch,
            const int* __restrict__ iflag,
            float* __restrict__ pooled, float* __restrict__ cnt, int N, int NG){
    int st=iflag[2];
    int wid=threadIdx.x>>6, lane=threadIdx.x&63;
    int n=blockIdx.x*4+wid; if(n>=N) return;
    int gi=batch[(size_t)n*st]; gi=gi<0?0:(gi>=NG?NG-1:gi);
    atomicAdd(&pooled[(size_t)gi*128+lane],    b2f(o[(size_t)n*128+lane]));
    atomicAdd(&pooled[(size_t)gi*128+64+lane], b2f(o[(size_t)n*128+64+lane]));
    if(lane==0) atomicAdd(&cnt[gi],1.f);
}
__global__ void final_k(const float* __restrict__ pooled, const float* __restrict__ cnt,
                        const float* __restrict__ oW, const float* __restrict__ ob,
                        float* __restrict__ out){
    int gi=blockIdx.x, lane=threadIdx.x;
    float v=pooled[(size_t)gi*128+lane]*oW[lane]
           +pooled[(size_t)gi*128+64+lane]*oW[64+lane];
    for(int m=32;m;m>>=1) v+=__shfl_xor(v,m,64);
    if(lane==0) out[gi]=v/fmaxf(cnt[gi],1.f)+ob[0];
}

// -------------------------------------------------------------------------------
template<typename TA>
static inline void gemm(hipStream_t s, const TA* A, int lda, int M, int K, int Kp,
                        const u16* Wp, const float* bias, u16* C, int act){
    dim3 grid((M+63)/64);
    if(act) gemm_k<TA,1><<<grid,256,0,s>>>(A,lda,M,K,Kp,Wp,bias,C);
    else    gemm_k<TA,0><<<grid,256,0,s>>>(A,lda,M,K,Kp,Wp,bias,C);
}

static inline void build_csr(hipStream_t s, const int* idx, int fi, const int* iflag,
                             int Ne, int Nn, int* off, int* cur, int* list, int* tot){
    int nb=(Nn+SCH-1)/SCH;
    zero_i_k<<<256,256,0,s>>>(cur,Nn);
    hist_k<<<(Ne+255)/256,256,0,s>>>(idx,iflag,fi,cur,Ne,Nn);
    scan1_k<<<nb,256,0,s>>>(cur,tot,Nn);
    scan2_k<<<1,1,0,s>>>(tot,nb);
    scan3_k<<<nb,256,0,s>>>(cur,tot,off,Nn,Ne);
    zero_i_k<<<256,256,0,s>>>(cur,Nn);
    fill_k<<<(Ne+255)/256,256,0,s>>>(idx,iflag,fi,off,cur,list,Ne,Nn);
}

static inline void pack_w(hipStream_t s, const float* W, u16* Wp, int K, int Kp){
    pack_w_k<<<(128*Kp+255)/256,256,0,s>>>(W,Wp,K,Kp);
}

extern "C" void kernel_launch(void* const* d_in, const int* in_sizes, int n_in,
                              void* d_out, int out_size, void* d_ws, size_t ws_size,
                              hipStream_t stream)
{
    const float* x_in =(const float*)d_in[0];
    const float* ea   =(const float*)d_in[1];
    const float* eal  =(const float*)d_in[2];
    const int*   ei   =(const int*)d_in[3];
    const int*   eil  =(const int*)d_in[4];
    const int*   batch=(const int*)d_in[5];
    const float* pre1W=(const float*)d_in[6];  const float* pre1b=(const float*)d_in[7];
    const float* pre2W=(const float*)d_in[8];  const float* pre2b=(const float*)d_in[9];
    const float* pre3W=(const float*)d_in[10]; const float* pre3b=(const float*)d_in[11];
    const float* lWsrc=(const float*)d_in[12]; const float* lbsrc=(const float*)d_in[13];
    const float* lWdst=(const float*)d_in[14]; const float* lbdst=(const float*)d_in[15];
    const float* lWe  =(const float*)d_in[16]; const float* lbe  =(const float*)d_in[17];
    const float* lnxg =(const float*)d_in[18]; const float* lnxb =(const float*)d_in[19];
    const float* lneg =(const float*)d_in[20]; const float* lneb =(const float*)d_in[21];
    const float* aWsrc=(const float*)d_in[22]; const float* absrc=(const float*)d_in[23];
    const float* aWdst=(const float*)d_in[24]; const float* abdst=(const float*)d_in[25];
    const float* aWe  =(const float*)d_in[26]; const float* abe  =(const float*)d_in[27];
    const float* anxg =(const float*)d_in[28]; const float* anxb =(const float*)d_in[29];
    const float* aneg =(const float*)d_in[30]; const float* aneb =(const float*)d_in[31];
    const float* bng  =(const float*)d_in[32]; const float* bnb  =(const float*)d_in[33];
    const float* postW=(const float*)d_in[34]; const float* postb=(const float*)d_in[35];
    const float* outW =(const float*)d_in[36]; const float* outb =(const float*)d_in[37];
    (void)n_in;

    const int N =in_sizes[5];
    const int E =in_sizes[3]/2;
    const int EL=in_sizes[4]/2;
    const int NG=out_size;
    const int CH=(E+1)/2;

    char* base=(char*)d_ws;
    size_t off=0;
    auto alloc=[&](size_t bytes)->char*{
        char* p=base+off; off=(off+bytes+255)&~(size_t)255; return p;
    };
    u16* hN   =(u16*)alloc((size_t)N*128*2);
    u16* hE   =(u16*)alloc((size_t)E*128*2);
    u16* hL   =(u16*)alloc((size_t)EL*128*2);
    u16* U    =(u16*)alloc((size_t)E*128*2);
    u16* P1   =(u16*)alloc((size_t)CH*128*2);     // also post-FC output
    int* off_l=(int*)alloc((size_t)(E+1)*4);
    int* cur_l=(int*)alloc((size_t)E*4);
    int* list_l=(int*)alloc((size_t)EL*4);
    int* off_a=(int*)alloc((size_t)(N+1)*4);
    int* cur_a=(int*)alloc((size_t)N*4);
    int* list_a=(int*)alloc((size_t)E*4);
    int* tot  =(int*)alloc(4096);
    int* iflag=(int*)alloc(64);
    float* stats =(float*)alloc(256*4);
    float* pooled=(float*)alloc((size_t)NG*128*4);
    float* cnt   =(float*)alloc((size_t)NG*4);
    u16* pre1p=(u16*)alloc(128*128*2);
    u16* pre2p=(u16*)alloc(128*64*2);
    u16* pre3p=(u16*)alloc(128*64*2);
    u16* postp=(u16*)alloc(128*128*2);
    u16 *lsrcp[4],*ldstp[4],*lWep[4],*asrcp[4],*adstp[4],*aWep[4];
    for(int i=0;i<4;i++){
        lsrcp[i]=(u16*)alloc(128*128*2);
        ldstp[i]=(u16*)alloc(128*128*2);
        lWep[i] =(u16*)alloc(128*384*2);
        asrcp[i]=(u16*)alloc(128*128*2);
        adstp[i]=(u16*)alloc(128*128*2);
        aWep[i] =(u16*)alloc(128*384*2);
    }
    if(off>ws_size){
        diag_k<<<(NG+255)/256,256,0,stream>>>((float*)d_out,NG,(float)(ws_size>>20)+0.25f);
        return;
    }

    probe_k<<<1,64,0,stream>>>(ei,eil,batch,N,iflag);
    build_csr(stream,eil,1,iflag,EL,E,off_l,cur_l,list_l,tot);
    build_csr(stream,ei, 0,iflag,E, N,off_a,cur_a,list_a,tot);

    pack_w(stream,pre1W,pre1p,92,128);
    pack_w(stream,pre2W,pre2p,50,64);
    pack_w(stream,pre3W,pre3p,40,64);
    pack_w(stream,postW,postp,128,128);
    for(int i=0;i<4;i++){
        pack_w(stream,lWsrc+(size_t)i*128*128,lsrcp[i],128,128);
        pack_w(stream,lWdst+(size_t)i*128*128,ldstp[i],128,128);
        pack_w(stream,lWe  +(size_t)i*384*128,lWep[i],384,384);
        pack_w(stream,aWsrc+(size_t)i*128*128,asrcp[i],128,128);
        pack_w(stream,aWdst+(size_t)i*128*128,adstp[i],128,128);
        pack_w(stream,aWe  +(size_t)i*384*128,aWep[i],384,384);
    }

    gemm(stream,x_in,92,N, 92,128,pre1p,pre1b,hN,1);
    gemm(stream,ea,  50,E, 50, 64,pre2p,pre2b,hE,1);
    gemm(stream,eal, 40,EL,40, 64,pre3p,pre3b,hL,1);

    for(int l=0;l<NCONV_DEF;++l){
        {   // ===== line conv: nodes=hE (E), edges=hL (EL) =====
            gemm(stream,hE,128,CH,128,128,ldstp[l],lbdst+l*128,P1,0);
            gather_k<0,0><<<(E+3)/4,256,0,stream>>>(hL,P1,U,off_l,list_l,
                                                    eil,EL,iflag,1,E,0,CH);
            gemm(stream,hE+(size_t)CH*128,128,E-CH,128,128,ldstp[l],lbdst+l*128,P1,0);
            gather_k<1,1><<<(E+3)/4,256,0,stream>>>(hL,P1,U,off_l,list_l,
                                                    eil,EL,iflag,1,E,CH,E);
            edgez_k<<<(EL+63)/64,256,0,stream>>>(hL,hE,eil,EL,iflag,1,
                                                 lWep[l],lbe+l*128,lneg+l*128,lneb+l*128,EL,E);
            gemmz_k<<<(E+63)/64,256,0,stream>>>(hE,E,lsrcp[l],lbsrc+l*128,U,
                                                lnxg+l*128,lnxb+l*128);
        }
        {   // ===== atom conv: nodes=hN (N), edges=hE (E) =====
            gemm(stream,hN,128,N,128,128,adstp[l],abdst+l*128,P1,0);
            gather_k<1,0><<<(N+3)/4,256,0,stream>>>(hE,P1,U,off_a,list_a,
                                                    ei,E,iflag,0,N,0,N);
            edgez_k<<<(E+63)/64,256,0,stream>>>(hE,hN,ei,E,iflag,0,
                                                aWep[l],abe+l*128,aneg+l*128,aneb+l*128,E,N);
            gemmz_k<<<(N+63)/64,256,0,stream>>>(hN,N,asrcp[l],absrc+l*128,U,
                                                anxg+l*128,anxb+l*128);
        }
    }

    zero_f_k<<<64,256,0,stream>>>(stats,256);
    zero_f_k<<<64,256,0,stream>>>(pooled,(long)NG*128);
    zero_f_k<<<1,256,0,stream>>>(cnt,NG);
    bn_stats_k<<<256,256,0,stream>>>(hN,stats,N);
    bn_apply_k<<<(N*128+255)/256,256,0,stream>>>(hN,stats,bng,bnb,N);

    gemm(stream,hN,128,N,128,128,postp,postb,P1,1);

    pool_k<<<(N+3)/4,256,0,stream>>>(P1,batch,iflag,pooled,cnt,N,NG);
    final_k<<<NG,64,0,stream>>>(pooled,cnt,outW,outb,(float*)d_out);
}